// Round 3
// baseline (294.909 us; speedup 1.0000x reference)
//
#include <hip/hip_runtime.h>
#include <cstdint>
#include <cstddef>

// ---------------- types / helpers ----------------
typedef unsigned short u16;
typedef u16   u16x8 __attribute__((ext_vector_type(8)));
typedef u16   u16x4 __attribute__((ext_vector_type(4)));
typedef u16   u16x2 __attribute__((ext_vector_type(2)));
typedef float f32x4 __attribute__((ext_vector_type(4)));

#define S_LEN 2048

static __device__ __forceinline__ u16 f2bf(float f){
  union { float f; unsigned u; } v; v.f = f;
  unsigned r = (v.u + 0x7FFFu + ((v.u >> 16) & 1u)) >> 16;   // RNE
  return (u16)r;
}
static __device__ __forceinline__ float bf2f(u16 u){
  union { unsigned u; float f; } v; v.u = ((unsigned)u) << 16; return v.f;
}

// mfma_f32_16x16x32_bf16 via inline asm (avoids builtin signature ambiguity).
// s_nop 1 covers VALU-write -> MFMA-read(srcC) hazard (asm is opaque to the
// compiler's hazard recognizer).
// Layout used consistently (m89/m91-verified C/D map):
//   A: lane holds A[lane&15][8*(lane>>4)+j]   (8 contiguous k)
//   B: lane holds B[8*(lane>>4)+j][lane&15]
//   D: lane reg r holds D[4*(lane>>4)+r][lane&15]
static __device__ __forceinline__ void mfma16(f32x4& c, u16x8 a, u16x8 b){
  asm("s_nop 1\n\tv_mfma_f32_16x16x32_bf16 %0, %1, %2, %0"
      : "+v"(c) : "v"(a), "v"(b));
}

#if defined(__has_builtin)
#  if __has_builtin(__builtin_amdgcn_global_load_lds)
#    define USE_GLDS 1
#  endif
#endif

static __device__ __forceinline__ void stage16(const u16* g, u16* l){
#ifdef USE_GLDS
  __builtin_amdgcn_global_load_lds((const __attribute__((address_space(1))) void*)g,
                                   (__attribute__((address_space(3))) void*)l,
                                   16, 0, 0);
#else
  *(u16x8*)l = *(const u16x8*)g;   // reg-staged fallback
#endif
}

// ---------------- prep kernels ----------------
__global__ __launch_bounds__(256) void cvt_x_kernel(const float* __restrict__ x,
                                                    u16* __restrict__ xb){
  int i = (blockIdx.x * 256 + threadIdx.x) * 4;
  float4 v = *(const float4*)(x + i);
  u16x4 o; o[0] = f2bf(v.x); o[1] = f2bf(v.y); o[2] = f2bf(v.z); o[3] = f2bf(v.w);
  *(u16x4*)(xb + i) = o;
}

// W[K][N] f32  ->  WT[N][K] bf16 (scaled)
__global__ __launch_bounds__(256) void transpose_w(const float* __restrict__ W,
                                                   u16* __restrict__ WT,
                                                   int K, int N, float scale){
  __shared__ float tile[32][33];
  int n0 = blockIdx.x * 32, k0 = blockIdx.y * 32;
  int tx = threadIdx.x, ty = threadIdx.y;     // block (32,8)
  #pragma unroll
  for (int i = 0; i < 32; i += 8)
    tile[ty + i][tx] = W[(size_t)(k0 + ty + i) * N + n0 + tx];
  __syncthreads();
  #pragma unroll
  for (int i = 0; i < 32; i += 8)
    WT[(size_t)(n0 + ty + i) * K + k0 + tx] = f2bf(scale * tile[tx][ty + i]);
}

// ---------------- GEMM: C = A(bf16 MxK) @ BT(bf16 NxK)^T ----------------
// MODE 0: N=2048, cols 0..1023 -> q (rope), 1024..2047 -> k (rope); writes [h][s][kd]
// MODE 1: N=4096, cols 0..2047 -> vT[n][s], 2048..4095 -> g[s][n-2048]
// MODE 2: N=1024, f32 row-major out
template<int MODE>
__global__ __launch_bounds__(256) void gemm_k(
    const u16* __restrict__ A, const u16* __restrict__ BT, int K,
    float* __restrict__ outF,
    u16* __restrict__ oq, u16* __restrict__ ok,
    u16* __restrict__ ovT, u16* __restrict__ og,
    const float* __restrict__ sinb, const float* __restrict__ cosb)
{
  __shared__ u16 lA[128 * 32];
  __shared__ u16 lB[128 * 32];
  const int t = threadIdx.x;
  const int lane = t & 63, w = t >> 6;
  const int r = lane & 15, g4 = lane >> 4;
  const int bm = blockIdx.y * 128, bn = blockIdx.x * 128;
  const int wm = (w & 1) * 64, wn = (w >> 1) * 64;

  const u16* ga = A  + (size_t)(bm + (t >> 2)) * K + (t & 3) * 8;
  const u16* gb = BT + (size_t)(bn + (t >> 2)) * K + (t & 3) * 8;
  u16* la = &lA[t * 8];
  u16* lb = &lB[t * 8];

  f32x4 acc[4][4] = {};

  for (int kb = 0; kb < K; kb += 32){
    stage16(ga + kb,                      la);
    stage16(ga + (size_t)64 * K + kb,     la + 2048);
    stage16(gb + kb,                      lb);
    stage16(gb + (size_t)64 * K + kb,     lb + 2048);
    asm volatile("s_waitcnt vmcnt(0)" ::: "memory");
    __syncthreads();
    u16x8 af[4], bf[4];
    #pragma unroll
    for (int i = 0; i < 4; ++i)
      af[i] = *(const u16x8*)&lA[(wm + 16 * i + r) * 32 + 8 * g4];
    #pragma unroll
    for (int i = 0; i < 4; ++i)
      bf[i] = *(const u16x8*)&lB[(wn + 16 * i + r) * 32 + 8 * g4];
    #pragma unroll
    for (int mi = 0; mi < 4; ++mi)
      #pragma unroll
      for (int ni = 0; ni < 4; ++ni)
        mfma16(acc[mi][ni], af[mi], bf[ni]);
    __syncthreads();
  }

  if constexpr (MODE == 2){
    #pragma unroll
    for (int mi = 0; mi < 4; ++mi)
      #pragma unroll
      for (int ni = 0; ni < 4; ++ni)
        #pragma unroll
        for (int rr = 0; rr < 4; ++rr){
          int row = bm + wm + 16 * mi + 4 * g4 + rr;
          int col = bn + wn + 16 * ni + r;
          outF[(size_t)row * 1024 + col] = acc[mi][ni][rr];
        }
  } else if constexpr (MODE == 0){
    #pragma unroll
    for (int mi = 0; mi < 4; ++mi)
      #pragma unroll
      for (int ni = 0; ni < 4; ++ni){
        int n = bn + wn + 16 * ni + r;
        int kd = n & 63;
        #pragma unroll
        for (int rr = 0; rr < 4; ++rr){
          int srow = bm + wm + 16 * mi + 4 * g4 + rr;
          float v = acc[mi][ni][rr];
          float pv = __shfl_xor(v, 1);               // rope partner col (n^1)
          float cs = cosb[srow * 64 + kd];
          float sn = sinb[srow * 64 + kd];
          float o = v * cs + ((n & 1) ? pv : -pv) * sn;
          u16 ob = f2bf(o);
          if (n < 1024) oq[((size_t)(n >> 6)          * S_LEN + srow) * 64 + kd] = ob;
          else          ok[((size_t)((n - 1024) >> 6) * S_LEN + srow) * 64 + kd] = ob;
        }
      }
  } else { // MODE 1
    #pragma unroll
    for (int mi = 0; mi < 4; ++mi)
      #pragma unroll
      for (int ni = 0; ni < 4; ++ni){
        int n = bn + wn + 16 * ni + r;
        int srow0 = bm + wm + 16 * mi + 4 * g4;
        if (n < 2048){
          u16x4 pk;
          #pragma unroll
          for (int rr = 0; rr < 4; ++rr) pk[rr] = f2bf(acc[mi][ni][rr]);
          *(u16x4*)&ovT[(size_t)n * S_LEN + srow0] = pk;   // vT[n][s..s+3]
        } else {
          #pragma unroll
          for (int rr = 0; rr < 4; ++rr)
            og[(size_t)(srow0 + rr) * 2048 + (n - 2048)] = f2bf(acc[mi][ni][rr]);
        }
      }
  }
}

// ---------------- retention ----------------
// grid (S/16, H), 1 wave/block. Mask computed on the fly; den applied at end.
__global__ __launch_bounds__(64) void retention(const u16* __restrict__ qrb,
                                                const u16* __restrict__ krb,
                                                const u16* __restrict__ vTb,
                                                float* __restrict__ obuf){
  const int h  = blockIdx.y;
  const int s0 = blockIdx.x * 16;
  const int lane = threadIdx.x;
  const int r = lane & 15, g4 = lane >> 4;
  __shared__ u16 pbuf[16 * 88];    // [16 s][64 t], stride 88 (16B-aligned rows)

  const float om    = exp2f(-5.0f - (float)h);   // 1-gamma, exact
  const float gamma = 1.0f - om;
  const float lg    = logf(gamma);
  const float l2g   = lg * 1.44269504088896f;

  const u16* qrow = qrb + ((size_t)h * S_LEN + (s0 + r)) * 64 + 8 * g4;
  u16x8 qf0 = *(const u16x8*)(qrow);
  u16x8 qf1 = *(const u16x8*)(qrow + 32);

  float invn[4], rs[4] = {0.f, 0.f, 0.f, 0.f};
  #pragma unroll
  for (int rr = 0; rr < 4; ++rr){
    int s = s0 + 4 * g4 + rr;
    float sum = -expm1f((float)(s + 1) * lg) / om;   // (1-g^{s+1})/(1-g), stable
    invn[rr] = rsqrtf(sum);
  }
  f32x4 oacc[8] = {};

  // skip tiles with decay < 2^-30
  float span = 30.0f / (-l2g);
  int t0 = 0;
  float tf = (float)(s0 - 63) - span;
  if (tf > 0.0f) t0 = ((int)tf) & ~63;

  for (int tb = t0; tb <= s0 + 15; tb += 64){
    f32x4 p[4] = {};
    #pragma unroll
    for (int sub = 0; sub < 4; ++sub){
      const u16* krow = krb + ((size_t)h * S_LEN + (tb + 16 * sub + r)) * 64 + 8 * g4;
      u16x8 kf0 = *(const u16x8*)(krow);
      u16x8 kf1 = *(const u16x8*)(krow + 32);
      mfma16(p[sub], qf0, kf0);
      mfma16(p[sub], qf1, kf1);
    }
    // MFMA -> VALU read hazard fence (pass-through keeps ordering)
    asm volatile("s_nop 7\n\ts_nop 7"
                 : "+v"(p[0]), "+v"(p[1]), "+v"(p[2]), "+v"(p[3]));
    #pragma unroll
    for (int sub = 0; sub < 4; ++sub){
      int tt = tb + 16 * sub + r;
      #pragma unroll
      for (int rr = 0; rr < 4; ++rr){
        int d = (s0 + 4 * g4 + rr) - tt;
        float dec = 0.0f;
        if (d >= 0) dec = exp2f((float)d * l2g) * invn[rr];
        float val = p[sub][rr] * dec;
        rs[rr] += val;
        pbuf[(4 * g4 + rr) * 88 + 16 * sub + r] = f2bf(val);
      }
    }
    __syncthreads();
    u16x8 pf0 = *(const u16x8*)&pbuf[r * 88 + 8 * g4];
    u16x8 pf1 = *(const u16x8*)&pbuf[r * 88 + 32 + 8 * g4];
    const u16* vbase = vTb + ((size_t)h * 128 + r) * S_LEN + tb + 8 * g4;
    #pragma unroll
    for (int cs = 0; cs < 8; ++cs){
      const u16* vrow = vbase + (size_t)(16 * cs) * S_LEN;
      mfma16(oacc[cs], pf0, *(const u16x8*)(vrow));
      mfma16(oacc[cs], pf1, *(const u16x8*)(vrow + 32));
    }
    __syncthreads();
  }

  #pragma unroll
  for (int rr = 0; rr < 4; ++rr){
    float v = rs[rr];
    v += __shfl_xor(v, 1); v += __shfl_xor(v, 2);
    v += __shfl_xor(v, 4); v += __shfl_xor(v, 8);
    float den = fabsf(v); if (den < 1.0f) den = 1.0f;
    rs[rr] = 1.0f / den;
  }
  #pragma unroll
  for (int cs = 0; cs < 8; ++cs)
    #pragma unroll
    for (int rr = 0; rr < 4; ++rr){
      int s = s0 + 4 * g4 + rr;
      obuf[((size_t)h * S_LEN + s) * 128 + 16 * cs + r] = oacc[cs][rr] * rs[rr];
    }
}

// ---------------- groupnorm + silu gate ----------------
__global__ __launch_bounds__(256) void gn_gate_kernel(const float* __restrict__ obuf,
                                                      const u16* __restrict__ gb,
                                                      const float* __restrict__ gnw,
                                                      const float* __restrict__ gnb,
                                                      u16* __restrict__ gated){
  int s = blockIdx.x;
  int w = threadIdx.x >> 6, lane = threadIdx.x & 63;
  for (int h = w; h < 16; h += 4){
    const float* op = obuf + ((size_t)h * S_LEN + s) * 128 + lane * 2;
    float v0 = op[0], v1 = op[1];
    float sum = v0 + v1;
    #pragma unroll
    for (int m = 1; m < 64; m <<= 1) sum += __shfl_xor(sum, m);
    float mu = sum * (1.0f / 128.0f);
    float d0 = v0 - mu, d1 = v1 - mu;
    float sq = d0 * d0 + d1 * d1;
    #pragma unroll
    for (int m = 1; m < 64; m <<= 1) sq += __shfl_xor(sq, m);
    float rstd = rsqrtf(sq * (1.0f / 128.0f) + 1e-5f);
    int c = h * 128 + lane * 2;
    float n0 = d0 * rstd * gnw[c]     + gnb[c];
    float n1 = d1 * rstd * gnw[c + 1] + gnb[c + 1];
    u16x2 gv = *(const u16x2*)(gb + (size_t)s * 2048 + c);
    float g0 = bf2f(gv[0]), g1 = bf2f(gv[1]);
    float r0 = g0 / (1.0f + __expf(-g0)) * n0;   // g*sigmoid(g)*o
    float r1 = g1 / (1.0f + __expf(-g1)) * n1;
    u16x2 o2; o2[0] = f2bf(r0); o2[1] = f2bf(r1);
    *(u16x2*)(gated + (size_t)s * 2048 + c) = o2;
  }
}

// ---------------- launcher ----------------
extern "C" void kernel_launch(void* const* d_in, const int* in_sizes, int n_in,
                              void* d_out, int out_size, void* d_ws, size_t ws_size,
                              hipStream_t stream)
{
  (void)in_sizes; (void)n_in; (void)out_size; (void)ws_size;
  const float* x    = (const float*)d_in[0];
  const float* sinb = (const float*)d_in[1];
  const float* cosb = (const float*)d_in[2];
  // d_in[3] = mask : recomputed on the fly, never read (saves 268 MB)
  const float* Wq   = (const float*)d_in[4];
  const float* Wk   = (const float*)d_in[5];
  const float* Wv   = (const float*)d_in[6];
  const float* Wg   = (const float*)d_in[7];
  const float* Wo   = (const float*)d_in[8];
  const float* gnw  = (const float*)d_in[9];
  const float* gnb  = (const float*)d_in[10];
  float* out = (float*)d_out;

  // workspace layout (lifetime-overlapped, peak 44 MB)
  char* ws = (char*)d_ws;
  u16*   xb    = (u16*)  (ws + 0);                 // 4MB   (dead after L3)
  u16*   WqkT  = (u16*)  (ws + ((size_t)4  << 20)); // 4MB  (dead after L2)
  u16*   WvgT  = (u16*)  (ws + ((size_t)8  << 20)); // 8MB  (dead after L3)
  float* obuf  = (float*)(ws + 0);                 // 16MB  (L4 -> L5, reuses 0..16M)
  u16*   WoT   = (u16*)  (ws + ((size_t)16 << 20)); // 4MB
  u16*   qrb   = (u16*)  (ws + ((size_t)20 << 20)); // 4MB  (dead after L4)
  u16*   krb   = (u16*)  (ws + ((size_t)24 << 20)); // 4MB  (dead after L4)
  u16*   gated = (u16*)  (ws + ((size_t)20 << 20)); // 8MB  (L5 -> L6, reuses qr/kr)
  u16*   vTb   = (u16*)  (ws + ((size_t)28 << 20)); // 8MB
  u16*   gbuf  = (u16*)  (ws + ((size_t)36 << 20)); // 8MB

  // L1: prep — convert x, transpose+convert weights (fold k-scaling 1/8 into Wk)
  cvt_x_kernel<<<dim3(2048), dim3(256), 0, stream>>>(x, xb);
  transpose_w<<<dim3(32, 32), dim3(32, 8), 0, stream>>>(Wq, WqkT,                       1024, 1024, 1.0f);
  transpose_w<<<dim3(32, 32), dim3(32, 8), 0, stream>>>(Wk, WqkT + (size_t)1024 * 1024, 1024, 1024, 0.125f);
  transpose_w<<<dim3(64, 32), dim3(32, 8), 0, stream>>>(Wv, WvgT,                       1024, 2048, 1.0f);
  transpose_w<<<dim3(64, 32), dim3(32, 8), 0, stream>>>(Wg, WvgT + (size_t)2048 * 1024, 1024, 2048, 1.0f);
  transpose_w<<<dim3(32, 64), dim3(32, 8), 0, stream>>>(Wo, WoT,                        2048, 1024, 1.0f);

  // L2: q|k projection + rope  -> qrb, krb  [h][s][64] bf16
  gemm_k<0><<<dim3(16, 16), dim3(256), 0, stream>>>(xb, WqkT, 1024,
      nullptr, qrb, krb, nullptr, nullptr, sinb, cosb);

  // L3: v|g projection -> vTb [h*128+c][s], gbuf [s][2048]
  gemm_k<1><<<dim3(32, 16), dim3(256), 0, stream>>>(xb, WvgT, 1024,
      nullptr, nullptr, nullptr, vTb, gbuf, nullptr, nullptr);

  // L4: retention -> obuf [h][s][128] f32
  retention<<<dim3(128, 16), dim3(64), 0, stream>>>(qrb, krb, vTb, obuf);

  // L5: groupnorm + silu gate -> gated [s][2048] bf16
  gn_gate_kernel<<<dim3(2048), dim3(256), 0, stream>>>(obuf, gbuf, gnw, gnb, gated);

  // L6: final projection -> d_out f32 [2048][1024]
  gemm_k<2><<<dim3(8, 16), dim3(256), 0, stream>>>(gated, WoT, 2048,
      out, nullptr, nullptr, nullptr, nullptr, nullptr, nullptr);
}

// Round 4
// 178.575 us; speedup vs baseline: 1.6515x; 1.6515x over previous
//
#include <hip/hip_runtime.h>
#include <cstdint>
#include <cstddef>

// ---------------- types / helpers ----------------
typedef unsigned short u16;
typedef u16   u16x8 __attribute__((ext_vector_type(8)));
typedef u16   u16x4 __attribute__((ext_vector_type(4)));
typedef u16   u16x2 __attribute__((ext_vector_type(2)));
typedef float f32x4 __attribute__((ext_vector_type(4)));

#define S_LEN 2048

static __device__ __forceinline__ u16 f2bf(float f){
  union { float f; unsigned u; } v; v.f = f;
  unsigned r = (v.u + 0x7FFFu + ((v.u >> 16) & 1u)) >> 16;   // RNE
  return (u16)r;
}
static __device__ __forceinline__ float bf2f(u16 u){
  union { unsigned u; float f; } v; v.u = ((unsigned)u) << 16; return v.f;
}

// mfma_f32_16x16x32_bf16 via inline asm.
//   A: lane holds A[lane&15][8*(lane>>4)+j]
//   B: lane holds B[8*(lane>>4)+j][lane&15]
//   D: lane reg r holds D[4*(lane>>4)+r][lane&15]
static __device__ __forceinline__ void mfma16(f32x4& c, u16x8 a, u16x8 b){
  asm("s_nop 1\n\tv_mfma_f32_16x16x32_bf16 %0, %1, %2, %0"
      : "+v"(c) : "v"(a), "v"(b));
}

#if defined(__has_builtin)
#  if __has_builtin(__builtin_amdgcn_global_load_lds)
#    define USE_GLDS 1
#  endif
#endif

static __device__ __forceinline__ void stage16(const u16* g, u16* l){
#ifdef USE_GLDS
  __builtin_amdgcn_global_load_lds((const __attribute__((address_space(1))) void*)g,
                                   (__attribute__((address_space(3))) void*)l,
                                   16, 0, 0);
#else
  *(u16x8*)l = *(const u16x8*)g;   // reg-staged fallback
#endif
}

// ---------------- prep kernels ----------------
__global__ __launch_bounds__(256) void cvt_x_kernel(const float* __restrict__ x,
                                                    u16* __restrict__ xb){
  int i = (blockIdx.x * 256 + threadIdx.x) * 4;
  float4 v = *(const float4*)(x + i);
  u16x4 o; o[0] = f2bf(v.x); o[1] = f2bf(v.y); o[2] = f2bf(v.z); o[3] = f2bf(v.w);
  *(u16x4*)(xb + i) = o;
}

// W[K][N] f32  ->  WT[N][K] bf16 (scaled)
__global__ __launch_bounds__(256) void transpose_w(const float* __restrict__ W,
                                                   u16* __restrict__ WT,
                                                   int K, int N, float scale){
  __shared__ float tile[32][33];
  int n0 = blockIdx.x * 32, k0 = blockIdx.y * 32;
  int tx = threadIdx.x, ty = threadIdx.y;     // block (32,8)
  #pragma unroll
  for (int i = 0; i < 32; i += 8)
    tile[ty + i][tx] = W[(size_t)(k0 + ty + i) * N + n0 + tx];
  __syncthreads();
  #pragma unroll
  for (int i = 0; i < 32; i += 8)
    WT[(size_t)(n0 + ty + i) * K + k0 + tx] = f2bf(scale * tile[tx][ty + i]);
}

// ---------------- GEMM: C = A(bf16 MxK) @ BT(bf16 NxK)^T ----------------
template<int MODE>
__global__ __launch_bounds__(256) void gemm_k(
    const u16* __restrict__ A, const u16* __restrict__ BT, int K,
    float* __restrict__ outF,
    u16* __restrict__ oq, u16* __restrict__ ok,
    u16* __restrict__ ovT, u16* __restrict__ og,
    const float* __restrict__ sinb, const float* __restrict__ cosb)
{
  __shared__ u16 lA[128 * 32];
  __shared__ u16 lB[128 * 32];
  const int t = threadIdx.x;
  const int lane = t & 63, w = t >> 6;
  const int r = lane & 15, g4 = lane >> 4;
  const int bm = blockIdx.y * 128, bn = blockIdx.x * 128;
  const int wm = (w & 1) * 64, wn = (w >> 1) * 64;

  const u16* ga = A  + (size_t)(bm + (t >> 2)) * K + (t & 3) * 8;
  const u16* gb = BT + (size_t)(bn + (t >> 2)) * K + (t & 3) * 8;
  u16* la = &lA[t * 8];
  u16* lb = &lB[t * 8];

  f32x4 acc[4][4] = {};

  for (int kb = 0; kb < K; kb += 32){
    stage16(ga + kb,                      la);
    stage16(ga + (size_t)64 * K + kb,     la + 2048);
    stage16(gb + kb,                      lb);
    stage16(gb + (size_t)64 * K + kb,     lb + 2048);
    asm volatile("s_waitcnt vmcnt(0)" ::: "memory");
    __syncthreads();
    u16x8 af[4], bf[4];
    #pragma unroll
    for (int i = 0; i < 4; ++i)
      af[i] = *(const u16x8*)&lA[(wm + 16 * i + r) * 32 + 8 * g4];
    #pragma unroll
    for (int i = 0; i < 4; ++i)
      bf[i] = *(const u16x8*)&lB[(wn + 16 * i + r) * 32 + 8 * g4];
    #pragma unroll
    for (int mi = 0; mi < 4; ++mi)
      #pragma unroll
      for (int ni = 0; ni < 4; ++ni)
        mfma16(acc[mi][ni], af[mi], bf[ni]);
    __syncthreads();
  }

  if constexpr (MODE == 2){
    #pragma unroll
    for (int mi = 0; mi < 4; ++mi)
      #pragma unroll
      for (int ni = 0; ni < 4; ++ni)
        #pragma unroll
        for (int rr = 0; rr < 4; ++rr){
          int row = bm + wm + 16 * mi + 4 * g4 + rr;
          int col = bn + wn + 16 * ni + r;
          outF[(size_t)row * 1024 + col] = acc[mi][ni][rr];
        }
  } else if constexpr (MODE == 0){
    #pragma unroll
    for (int mi = 0; mi < 4; ++mi)
      #pragma unroll
      for (int ni = 0; ni < 4; ++ni){
        int n = bn + wn + 16 * ni + r;
        int kd = n & 63;
        #pragma unroll
        for (int rr = 0; rr < 4; ++rr){
          int srow = bm + wm + 16 * mi + 4 * g4 + rr;
          float v = acc[mi][ni][rr];
          float pv = __shfl_xor(v, 1);               // rope partner col (n^1)
          float cs = cosb[srow * 64 + kd];
          float sn = sinb[srow * 64 + kd];
          float o = v * cs + ((n & 1) ? pv : -pv) * sn;
          u16 ob = f2bf(o);
          if (n < 1024) oq[((size_t)(n >> 6)          * S_LEN + srow) * 64 + kd] = ob;
          else          ok[((size_t)((n - 1024) >> 6) * S_LEN + srow) * 64 + kd] = ob;
        }
      }
  } else { // MODE 1
    #pragma unroll
    for (int mi = 0; mi < 4; ++mi)
      #pragma unroll
      for (int ni = 0; ni < 4; ++ni){
        int n = bn + wn + 16 * ni + r;
        int srow0 = bm + wm + 16 * mi + 4 * g4;
        if (n < 2048){
          u16x4 pk;
          #pragma unroll
          for (int rr = 0; rr < 4; ++rr) pk[rr] = f2bf(acc[mi][ni][rr]);
          *(u16x4*)&ovT[(size_t)n * S_LEN + srow0] = pk;   // vT[n][s..s+3]
        } else {
          #pragma unroll
          for (int rr = 0; rr < 4; ++rr)
            og[(size_t)(srow0 + rr) * 2048 + (n - 2048)] = f2bf(acc[mi][ni][rr]);
        }
      }
  }
}

// ---------------- retention v2 ----------------
// 512 blocks x 4 waves. Block = (head h, 64 s-rows). K/V tiles double-buffered
// in LDS via global_load_lds (linear dest, XOR-swizzled global source);
// counted vmcnt(6); raw s_barrier. Wave w owns rows s0+16w..+15.
// Heavy/light pairing: idx<256 -> sb=31-(idx>>4) (heavy first), idx>=256 -> sb=(idx>>4)-16.
__global__ __launch_bounds__(256) void retention2(const u16* __restrict__ qrb,
                                                  const u16* __restrict__ krb,
                                                  const u16* __restrict__ vTb,
                                                  float* __restrict__ obuf){
  __shared__ u16 kt[2][64 * 64];    // [t-row 64][kd 64], chunk-swizzled
  __shared__ u16 vt[2][128 * 64];   // [c-row 128][t 64], chunk-swizzled
  __shared__ u16 pb[4][16 * 88];    // per-wave P transpose

  const int idx = blockIdx.x;
  const int h  = idx & 15;
  const int sb = (idx < 256) ? (31 - (idx >> 4)) : ((idx >> 4) - 16);
  const int s0 = sb * 64;
  const int t  = threadIdx.x;
  const int w  = t >> 6, lane = t & 63;
  const int r  = lane & 15, g4 = lane >> 4;
  const int s0w = s0 + 16 * w;

  const float om   = exp2f(-5.0f - (float)h);       // 1-gamma, exact
  const float lg   = logf(1.0f - om);
  const float l2g  = lg * 1.44269504088896f;        // negative
  const float dmax = 30.0f / (-l2g);

  // block-level first tile (decay skip, conservative floor)
  int t0 = 0;
  {
    float tf = (float)(s0 - 63) - dmax;
    if (tf > 0.0f) t0 = ((int)tf) & ~63;
  }

  // Q fragments for this wave's 16 rows
  const u16* qrow = qrb + ((size_t)h * S_LEN + (s0w + r)) * 64 + 8 * g4;
  u16x8 qf0 = *(const u16x8*)(qrow);
  u16x8 qf1 = *(const u16x8*)(qrow + 32);

  float invn[4];
  #pragma unroll
  for (int rr = 0; rr < 4; ++rr){
    int s = s0w + 4 * g4 + rr;
    invn[rr] = rsqrtf(-expm1f((float)(s + 1) * lg) / om);  // 1/sqrt((1-g^{s+1})/(1-g))
  }
  // hoisted within-tile decay factors: exp2(-(16*sub + r)*l2g)
  float bsub[4];
  {
    float e_r  = exp2f(-(float)r * l2g);
    float e16  = exp2f(-16.0f * l2g);
    bsub[0] = e_r; bsub[1] = bsub[0] * e16; bsub[2] = bsub[1] * e16; bsub[3] = bsub[2] * e16;
  }

  f32x4 oacc[8] = {};
  float rs[4] = {0.f, 0.f, 0.f, 0.f};

  // cooperative stage of one (K,V) tile pair into buffer `buf` at t-base tb.
  // LDS dest linear (chunk ci -> ci*16B); global source chunk XOR-swizzled so
  // reads at LDS[row][c ^ (row&7)] return global[row][c].
  auto STAGE = [&](int buf, int tb){
    #pragma unroll
    for (int p = 0; p < 2; ++p){                 // K: 512 chunks
      int ci = p * 256 + t;
      int row = ci >> 3, ch = ci & 7;
      const u16* src = krb + ((size_t)h * S_LEN + tb + row) * 64 + ((ch ^ (row & 7)) * 8);
      stage16(src, &kt[buf][ci * 8]);
    }
    #pragma unroll
    for (int p = 0; p < 4; ++p){                 // V: 1024 chunks
      int ci = p * 256 + t;
      int row = ci >> 3, ch = ci & 7;
      const u16* src = vTb + ((size_t)(h * 128 + row)) * S_LEN + tb + ((ch ^ (row & 7)) * 8);
      stage16(src, &vt[buf][ci * 8]);
    }
  };

  STAGE(0, t0);
  int cur = 0;
  for (int tb = t0; tb <= s0; tb += 64){
    const bool last = (tb + 64 > s0);
    if (!last){
      STAGE(cur ^ 1, tb + 64);                   // prefetch next tile (6 loads/thread)
      asm volatile("s_waitcnt vmcnt(6)" ::: "memory");   // current tile landed
    } else {
      asm volatile("s_waitcnt vmcnt(0)" ::: "memory");
    }
    __builtin_amdgcn_s_barrier();                // buf[cur] valid for all waves

    // wave-uniform causal / decay guard (barriers stay outside)
    if (tb <= s0w + 15 && (float)(s0w - tb - 63) <= dmax){
      // QK^T from LDS K
      f32x4 p[4] = {};
      #pragma unroll
      for (int sub = 0; sub < 4; ++sub){
        int row = 16 * sub + r;
        u16x8 kf0 = *(const u16x8*)&kt[cur][row * 64 + ((g4       ^ (row & 7)) * 8)];
        u16x8 kf1 = *(const u16x8*)&kt[cur][row * 64 + (((4 + g4) ^ (row & 7)) * 8)];
        mfma16(p[sub], qf0, kf0);
        mfma16(p[sub], qf1, kf1);
      }
      asm volatile("s_nop 7\n\ts_nop 7"          // MFMA -> VALU hazard fence
                   : "+v"(p[0]), "+v"(p[1]), "+v"(p[2]), "+v"(p[3]));
      float arr[4];
      #pragma unroll
      for (int rr = 0; rr < 4; ++rr)
        arr[rr] = exp2f((float)(s0w + 4 * g4 + rr - tb) * l2g) * invn[rr];
      #pragma unroll
      for (int sub = 0; sub < 4; ++sub){
        int tt = tb + 16 * sub + r;
        #pragma unroll
        for (int rr = 0; rr < 4; ++rr){
          int srow = s0w + 4 * g4 + rr;
          float dec = (srow >= tt) ? arr[rr] * bsub[sub] : 0.0f;
          float val = p[sub][rr] * dec;
          rs[rr] += val;
          pb[w][(4 * g4 + rr) * 88 + 16 * sub + r] = f2bf(val);
        }
      }
      // wave-local P transpose: per-wave lgkmcnt covers all 64 lanes' ds_writes
      asm volatile("s_waitcnt lgkmcnt(0)" ::: "memory");
      __builtin_amdgcn_sched_barrier(0);
      u16x8 pf0 = *(const u16x8*)&pb[w][r * 88 + 8 * g4];
      u16x8 pf1 = *(const u16x8*)&pb[w][r * 88 + 32 + 8 * g4];
      // PV from LDS V
      #pragma unroll
      for (int cs = 0; cs < 8; ++cs){
        int row = 16 * cs + r;
        u16x8 vf0 = *(const u16x8*)&vt[cur][row * 64 + ((g4       ^ (row & 7)) * 8)];
        u16x8 vf1 = *(const u16x8*)&vt[cur][row * 64 + (((4 + g4) ^ (row & 7)) * 8)];
        mfma16(oacc[cs], pf0, vf0);
        mfma16(oacc[cs], pf1, vf1);
      }
    }
    asm volatile("s_waitcnt lgkmcnt(0)" ::: "memory");
    __builtin_amdgcn_s_barrier();                // all waves done reading buf[cur]
    cur ^= 1;
  }

  #pragma unroll
  for (int rr = 0; rr < 4; ++rr){
    float v = rs[rr];
    v += __shfl_xor(v, 1); v += __shfl_xor(v, 2);
    v += __shfl_xor(v, 4); v += __shfl_xor(v, 8);
    float den = fabsf(v); if (den < 1.0f) den = 1.0f;
    rs[rr] = 1.0f / den;
  }
  #pragma unroll
  for (int cs = 0; cs < 8; ++cs)
    #pragma unroll
    for (int rr = 0; rr < 4; ++rr){
      int s = s0w + 4 * g4 + rr;
      obuf[((size_t)h * S_LEN + s) * 128 + 16 * cs + r] = oacc[cs][rr] * rs[rr];
    }
}

// ---------------- groupnorm + silu gate ----------------
__global__ __launch_bounds__(256) void gn_gate_kernel(const float* __restrict__ obuf,
                                                      const u16* __restrict__ gb,
                                                      const float* __restrict__ gnw,
                                                      const float* __restrict__ gnb,
                                                      u16* __restrict__ gated){
  int s = blockIdx.x;
  int w = threadIdx.x >> 6, lane = threadIdx.x & 63;
  for (int h = w; h < 16; h += 4){
    const float* op = obuf + ((size_t)h * S_LEN + s) * 128 + lane * 2;
    float v0 = op[0], v1 = op[1];
    float sum = v0 + v1;
    #pragma unroll
    for (int m = 1; m < 64; m <<= 1) sum += __shfl_xor(sum, m);
    float mu = sum * (1.0f / 128.0f);
    float d0 = v0 - mu, d1 = v1 - mu;
    float sq = d0 * d0 + d1 * d1;
    #pragma unroll
    for (int m = 1; m < 64; m <<= 1) sq += __shfl_xor(sq, m);
    float rstd = rsqrtf(sq * (1.0f / 128.0f) + 1e-5f);
    int c = h * 128 + lane * 2;
    float n0 = d0 * rstd * gnw[c]     + gnb[c];
    float n1 = d1 * rstd * gnw[c + 1] + gnb[c + 1];
    u16x2 gv = *(const u16x2*)(gb + (size_t)s * 2048 + c);
    float g0 = bf2f(gv[0]), g1 = bf2f(gv[1]);
    float r0 = g0 / (1.0f + __expf(-g0)) * n0;   // g*sigmoid(g)*o
    float r1 = g1 / (1.0f + __expf(-g1)) * n1;
    u16x2 o2; o2[0] = f2bf(r0); o2[1] = f2bf(r1);
    *(u16x2*)(gated + (size_t)s * 2048 + c) = o2;
  }
}

// ---------------- launcher ----------------
extern "C" void kernel_launch(void* const* d_in, const int* in_sizes, int n_in,
                              void* d_out, int out_size, void* d_ws, size_t ws_size,
                              hipStream_t stream)
{
  (void)in_sizes; (void)n_in; (void)out_size; (void)ws_size;
  const float* x    = (const float*)d_in[0];
  const float* sinb = (const float*)d_in[1];
  const float* cosb = (const float*)d_in[2];
  // d_in[3] = mask : recomputed on the fly, never read (saves 268 MB)
  const float* Wq   = (const float*)d_in[4];
  const float* Wk   = (const float*)d_in[5];
  const float* Wv   = (const float*)d_in[6];
  const float* Wg   = (const float*)d_in[7];
  const float* Wo   = (const float*)d_in[8];
  const float* gnw  = (const float*)d_in[9];
  const float* gnb  = (const float*)d_in[10];
  float* out = (float*)d_out;

  // workspace layout (lifetime-overlapped, peak 44 MB)
  char* ws = (char*)d_ws;
  u16*   xb    = (u16*)  (ws + 0);                  // 4MB   (dead after L3)
  u16*   WqkT  = (u16*)  (ws + ((size_t)4  << 20)); // 4MB   (dead after L2)
  u16*   WvgT  = (u16*)  (ws + ((size_t)8  << 20)); // 8MB   (dead after L3)
  float* obuf  = (float*)(ws + 0);                  // 16MB  (L4 -> L5)
  u16*   WoT   = (u16*)  (ws + ((size_t)16 << 20)); // 4MB
  u16*   qrb   = (u16*)  (ws + ((size_t)20 << 20)); // 4MB   (dead after L4)
  u16*   krb   = (u16*)  (ws + ((size_t)24 << 20)); // 4MB   (dead after L4)
  u16*   gated = (u16*)  (ws + ((size_t)20 << 20)); // 8MB   (L5 -> L6)
  u16*   vTb   = (u16*)  (ws + ((size_t)28 << 20)); // 8MB
  u16*   gbuf  = (u16*)  (ws + ((size_t)36 << 20)); // 8MB

  // L1: prep — convert x, transpose+convert weights (fold k-scaling 1/8 into Wk)
  cvt_x_kernel<<<dim3(2048), dim3(256), 0, stream>>>(x, xb);
  transpose_w<<<dim3(32, 32), dim3(32, 8), 0, stream>>>(Wq, WqkT,                       1024, 1024, 1.0f);
  transpose_w<<<dim3(32, 32), dim3(32, 8), 0, stream>>>(Wk, WqkT + (size_t)1024 * 1024, 1024, 1024, 0.125f);
  transpose_w<<<dim3(64, 32), dim3(32, 8), 0, stream>>>(Wv, WvgT,                       1024, 2048, 1.0f);
  transpose_w<<<dim3(64, 32), dim3(32, 8), 0, stream>>>(Wg, WvgT + (size_t)2048 * 1024, 1024, 2048, 1.0f);
  transpose_w<<<dim3(32, 64), dim3(32, 8), 0, stream>>>(Wo, WoT,                        2048, 1024, 1.0f);

  // L2: q|k projection + rope  -> qrb, krb  [h][s][64] bf16
  gemm_k<0><<<dim3(16, 16), dim3(256), 0, stream>>>(xb, WqkT, 1024,
      nullptr, qrb, krb, nullptr, nullptr, sinb, cosb);

  // L3: v|g projection -> vTb [h*128+c][s], gbuf [s][2048]
  gemm_k<1><<<dim3(32, 16), dim3(256), 0, stream>>>(xb, WvgT, 1024,
      nullptr, nullptr, nullptr, vTb, gbuf, nullptr, nullptr);

  // L4: retention -> obuf [h][s][128] f32
  retention2<<<dim3(512), dim3(256), 0, stream>>>(qrb, krb, vTb, obuf);

  // L5: groupnorm + silu gate -> gated [s][2048] bf16
  gn_gate_kernel<<<dim3(2048), dim3(256), 0, stream>>>(obuf, gbuf, gnw, gnb, gated);

  // L6: final projection -> d_out f32 [2048][1024]
  gemm_k<2><<<dim3(8, 16), dim3(256), 0, stream>>>(gated, WoT, 2048,
      out, nullptr, nullptr, nullptr, nullptr, nullptr, nullptr);
}

// Round 5
// 146.036 us; speedup vs baseline: 2.0194x; 1.2228x over previous
//
#include <hip/hip_runtime.h>
#include <cstdint>
#include <cstddef>

// ---------------- types / helpers ----------------
typedef unsigned short u16;
typedef u16   u16x8 __attribute__((ext_vector_type(8)));
typedef u16   u16x4 __attribute__((ext_vector_type(4)));
typedef u16   u16x2 __attribute__((ext_vector_type(2)));
typedef float f32x4 __attribute__((ext_vector_type(4)));

#define S_LEN 2048

static __device__ __forceinline__ u16 f2bf(float f){
  union { float f; unsigned u; } v; v.f = f;
  unsigned r = (v.u + 0x7FFFu + ((v.u >> 16) & 1u)) >> 16;   // RNE
  return (u16)r;
}
static __device__ __forceinline__ float bf2f(u16 u){
  union { unsigned u; float f; } v; v.u = ((unsigned)u) << 16; return v.f;
}

// mfma_f32_16x16x32_bf16 via inline asm.
//   A: lane holds A[lane&15][8*(lane>>4)+j]
//   B: lane holds B[8*(lane>>4)+j][lane&15]
//   D: lane reg r holds D[4*(lane>>4)+r][lane&15]
static __device__ __forceinline__ void mfma16(f32x4& c, u16x8 a, u16x8 b){
  asm("s_nop 1\n\tv_mfma_f32_16x16x32_bf16 %0, %1, %2, %0"
      : "+v"(c) : "v"(a), "v"(b));
}

#if defined(__has_builtin)
#  if __has_builtin(__builtin_amdgcn_global_load_lds)
#    define USE_GLDS 1
#  endif
#endif

static __device__ __forceinline__ void stage16(const u16* g, u16* l){
#ifdef USE_GLDS
  __builtin_amdgcn_global_load_lds((const __attribute__((address_space(1))) void*)g,
                                   (__attribute__((address_space(3))) void*)l,
                                   16, 0, 0);
#else
  *(u16x8*)l = *(const u16x8*)g;   // reg-staged fallback
#endif
}

// ---------------- prep kernels ----------------
__global__ __launch_bounds__(256) void cvt_x_kernel(const float* __restrict__ x,
                                                    u16* __restrict__ xb){
  int i = (blockIdx.x * 256 + threadIdx.x) * 4;
  float4 v = *(const float4*)(x + i);
  u16x4 o; o[0] = f2bf(v.x); o[1] = f2bf(v.y); o[2] = f2bf(v.z); o[3] = f2bf(v.w);
  *(u16x4*)(xb + i) = o;
}

// fused transpose of all 5 weights: W[K][N] f32 -> dst[N][K] bf16 (scaled)
// bid segments: [0,1024) Wq | [1024,2048) Wk(x0.125) | [2048,4096) Wv
//               [4096,6144) Wg | [6144,8192) Wo
__global__ __launch_bounds__(256) void transpose_all(
    const float* __restrict__ Wq, const float* __restrict__ Wk,
    const float* __restrict__ Wv, const float* __restrict__ Wg,
    const float* __restrict__ Wo, u16* __restrict__ WT, u16* __restrict__ WoT){
  __shared__ float tile[32][33];
  int bid = blockIdx.x;
  const float* W; u16* dst; int K, N, lb, lgx; float scale = 1.0f;
  if (bid < 1024)      { W=Wq; dst=WT;                        K=1024; N=1024; lb=bid;        lgx=5; }
  else if (bid < 2048) { W=Wk; dst=WT + (size_t)1024 * 1024;  K=1024; N=1024; lb=bid - 1024; lgx=5; scale=0.125f; }
  else if (bid < 4096) { W=Wv; dst=WT + (size_t)2048 * 1024;  K=1024; N=2048; lb=bid - 2048; lgx=6; }
  else if (bid < 6144) { W=Wg; dst=WT + (size_t)4096 * 1024;  K=1024; N=2048; lb=bid - 4096; lgx=6; }
  else                 { W=Wo; dst=WoT;                       K=2048; N=1024; lb=bid - 6144; lgx=5; }
  int n0 = (lb & ((1 << lgx) - 1)) * 32;
  int k0 = (lb >> lgx) * 32;
  int tx = threadIdx.x & 31, ty = threadIdx.x >> 5;   // 32x8
  #pragma unroll
  for (int i = 0; i < 32; i += 8)
    tile[ty + i][tx] = W[(size_t)(k0 + ty + i) * N + n0 + tx];
  __syncthreads();
  #pragma unroll
  for (int i = 0; i < 32; i += 8)
    dst[(size_t)(n0 + ty + i) * K + k0 + tx] = f2bf(scale * tile[tx][ty + i]);
}

// ---------------- pipelined GEMM: C = A(bf16 MxK) @ BT(bf16 NxK)^T -------------
// BM=128, BK=64, 4 waves (2m x 2n). Double-buffered LDS, global_load_lds with
// XOR chunk swizzle (linear LDS dest, pre-swizzled global source), counted
// vmcnt(TL) so next-tile loads fly across the barrier, raw s_barrier.
// MODE 0: merged projection epilogue over n in [0,6144):
//         [0,1024) q-rope -> oq[h][s][64]; [1024,2048) k-rope -> ok;
//         [2048,4096) vT[n-2048][s]; [4096,6144) g[s][n-4096]
// MODE 2: f32 row-major out (N=1024)
template<int MODE, int BN>
__global__ __launch_bounds__(256) void gemm2(
    const u16* __restrict__ A, const u16* __restrict__ BT, int K,
    float* __restrict__ outF,
    u16* __restrict__ oq, u16* __restrict__ ok,
    u16* __restrict__ ovT, u16* __restrict__ og,
    const float* __restrict__ sinb, const float* __restrict__ cosb)
{
  constexpr int NI = BN / 32;              // n-fragments per wave
  constexpr int LB_LOADS = BN * 8 / 256;   // lB chunks per thread
  constexpr int TL = 4 + LB_LOADS;         // loads per thread per tile

  __shared__ u16 lA[2][128 * 64];
  __shared__ u16 lB[2][BN * 64];

  const int t = threadIdx.x;
  const int lane = t & 63, w = t >> 6;
  const int r = lane & 15, g4 = lane >> 4;
  const int bm = blockIdx.y * 128, bn = blockIdx.x * BN;
  const int wm = (w & 1) * 64, wn = (w >> 1) * (BN / 2);

  f32x4 acc[4][NI] = {};

  auto STAGE = [&](int buf, int kb){
    #pragma unroll
    for (int p = 0; p < 4; ++p){                       // lA: 1024 chunks
      int ci = p * 256 + t;
      int row = ci >> 3, ch = ci & 7;
      stage16(A + (size_t)(bm + row) * K + kb + ((ch ^ (row & 7)) * 8),
              &lA[buf][ci * 8]);
    }
    #pragma unroll
    for (int p = 0; p < LB_LOADS; ++p){                // lB: BN*8 chunks
      int ci = p * 256 + t;
      int row = ci >> 3, ch = ci & 7;
      stage16(BT + (size_t)(bn + row) * K + kb + ((ch ^ (row & 7)) * 8),
              &lB[buf][ci * 8]);
    }
  };

  STAGE(0, 0);
  int cur = 0;
  for (int kb = 0; kb < K; kb += 64){
    if (kb + 64 < K){
      STAGE(cur ^ 1, kb + 64);                         // prefetch next tile
      if constexpr (TL == 8) asm volatile("s_waitcnt vmcnt(8)" ::: "memory");
      else                   asm volatile("s_waitcnt vmcnt(6)" ::: "memory");
    } else {
      asm volatile("s_waitcnt vmcnt(0)" ::: "memory");
    }
    __builtin_amdgcn_s_barrier();                      // buf[cur] valid

    #pragma unroll
    for (int j = 0; j < 2; ++j){                       // two K=32 sub-steps
      u16x8 af[4], bfr[NI];
      #pragma unroll
      for (int i = 0; i < 4; ++i){
        int row = wm + 16 * i + r;
        af[i] = *(const u16x8*)&lA[cur][row * 64 + (((j * 4 + g4) ^ (row & 7)) * 8)];
      }
      #pragma unroll
      for (int i = 0; i < NI; ++i){
        int row = wn + 16 * i + r;
        bfr[i] = *(const u16x8*)&lB[cur][row * 64 + (((j * 4 + g4) ^ (row & 7)) * 8)];
      }
      #pragma unroll
      for (int mi = 0; mi < 4; ++mi)
        #pragma unroll
        for (int ni = 0; ni < NI; ++ni)
          mfma16(acc[mi][ni], af[mi], bfr[ni]);
    }
    asm volatile("s_waitcnt lgkmcnt(0)" ::: "memory"); // reads drained
    __builtin_amdgcn_s_barrier();                      // safe to overwrite buf[cur]
    cur ^= 1;
  }

  if constexpr (MODE == 2){
    #pragma unroll
    for (int mi = 0; mi < 4; ++mi)
      #pragma unroll
      for (int ni = 0; ni < NI; ++ni)
        #pragma unroll
        for (int rr = 0; rr < 4; ++rr){
          int row = bm + wm + 16 * mi + 4 * g4 + rr;
          int col = bn + wn + 16 * ni + r;
          outF[(size_t)row * 1024 + col] = acc[mi][ni][rr];
        }
  } else {
    if (bn < 2048){                                    // q | k with rope
      #pragma unroll
      for (int mi = 0; mi < 4; ++mi)
        #pragma unroll
        for (int ni = 0; ni < NI; ++ni){
          int n = bn + wn + 16 * ni + r;
          int kd = n & 63;
          #pragma unroll
          for (int rr = 0; rr < 4; ++rr){
            int srow = bm + wm + 16 * mi + 4 * g4 + rr;
            float v = acc[mi][ni][rr];
            float pv = __shfl_xor(v, 1);               // rope partner col (n^1)
            float cs = cosb[srow * 64 + kd];
            float sn = sinb[srow * 64 + kd];
            float o = v * cs + ((n & 1) ? pv : -pv) * sn;
            u16 ob = f2bf(o);
            if (n < 1024) oq[((size_t)(n >> 6)          * S_LEN + srow) * 64 + kd] = ob;
            else          ok[((size_t)((n - 1024) >> 6) * S_LEN + srow) * 64 + kd] = ob;
          }
        }
    } else if (bn < 4096){                             // vT[n][s]
      #pragma unroll
      for (int mi = 0; mi < 4; ++mi)
        #pragma unroll
        for (int ni = 0; ni < NI; ++ni){
          int n = (bn - 2048) + wn + 16 * ni + r;
          int srow0 = bm + wm + 16 * mi + 4 * g4;
          u16x4 pk;
          #pragma unroll
          for (int rr = 0; rr < 4; ++rr) pk[rr] = f2bf(acc[mi][ni][rr]);
          *(u16x4*)&ovT[(size_t)n * S_LEN + srow0] = pk;
        }
    } else {                                           // g[s][n]
      #pragma unroll
      for (int mi = 0; mi < 4; ++mi)
        #pragma unroll
        for (int ni = 0; ni < NI; ++ni){
          int n = (bn - 4096) + wn + 16 * ni + r;
          int srow0 = bm + wm + 16 * mi + 4 * g4;
          #pragma unroll
          for (int rr = 0; rr < 4; ++rr)
            og[(size_t)(srow0 + rr) * 2048 + n] = f2bf(acc[mi][ni][rr]);
        }
    }
  }
}

// ---------------- retention v2 (unchanged from R3) ----------------
__global__ __launch_bounds__(256) void retention2(const u16* __restrict__ qrb,
                                                  const u16* __restrict__ krb,
                                                  const u16* __restrict__ vTb,
                                                  float* __restrict__ obuf){
  __shared__ u16 kt[2][64 * 64];    // [t-row 64][kd 64], chunk-swizzled
  __shared__ u16 vt[2][128 * 64];   // [c-row 128][t 64], chunk-swizzled
  __shared__ u16 pb[4][16 * 88];    // per-wave P transpose

  const int idx = blockIdx.x;
  const int h  = idx & 15;
  const int sb = (idx < 256) ? (31 - (idx >> 4)) : ((idx >> 4) - 16);
  const int s0 = sb * 64;
  const int t  = threadIdx.x;
  const int w  = t >> 6, lane = t & 63;
  const int r  = lane & 15, g4 = lane >> 4;
  const int s0w = s0 + 16 * w;

  const float om   = exp2f(-5.0f - (float)h);       // 1-gamma, exact
  const float lg   = logf(1.0f - om);
  const float l2g  = lg * 1.44269504088896f;        // negative
  const float dmax = 30.0f / (-l2g);

  int t0 = 0;
  {
    float tf = (float)(s0 - 63) - dmax;
    if (tf > 0.0f) t0 = ((int)tf) & ~63;
  }

  const u16* qrow = qrb + ((size_t)h * S_LEN + (s0w + r)) * 64 + 8 * g4;
  u16x8 qf0 = *(const u16x8*)(qrow);
  u16x8 qf1 = *(const u16x8*)(qrow + 32);

  float invn[4];
  #pragma unroll
  for (int rr = 0; rr < 4; ++rr){
    int s = s0w + 4 * g4 + rr;
    invn[rr] = rsqrtf(-expm1f((float)(s + 1) * lg) / om);
  }
  float bsub[4];
  {
    float e_r  = exp2f(-(float)r * l2g);
    float e16  = exp2f(-16.0f * l2g);
    bsub[0] = e_r; bsub[1] = bsub[0] * e16; bsub[2] = bsub[1] * e16; bsub[3] = bsub[2] * e16;
  }

  f32x4 oacc[8] = {};
  float rs[4] = {0.f, 0.f, 0.f, 0.f};

  auto STAGE = [&](int buf, int tb){
    #pragma unroll
    for (int p = 0; p < 2; ++p){                 // K: 512 chunks
      int ci = p * 256 + t;
      int row = ci >> 3, ch = ci & 7;
      const u16* src = krb + ((size_t)h * S_LEN + tb + row) * 64 + ((ch ^ (row & 7)) * 8);
      stage16(src, &kt[buf][ci * 8]);
    }
    #pragma unroll
    for (int p = 0; p < 4; ++p){                 // V: 1024 chunks
      int ci = p * 256 + t;
      int row = ci >> 3, ch = ci & 7;
      const u16* src = vTb + ((size_t)(h * 128 + row)) * S_LEN + tb + ((ch ^ (row & 7)) * 8);
      stage16(src, &vt[buf][ci * 8]);
    }
  };

  STAGE(0, t0);
  int cur = 0;
  for (int tb = t0; tb <= s0; tb += 64){
    const bool last = (tb + 64 > s0);
    if (!last){
      STAGE(cur ^ 1, tb + 64);
      asm volatile("s_waitcnt vmcnt(6)" ::: "memory");
    } else {
      asm volatile("s_waitcnt vmcnt(0)" ::: "memory");
    }
    __builtin_amdgcn_s_barrier();

    if (tb <= s0w + 15 && (float)(s0w - tb - 63) <= dmax){
      f32x4 p[4] = {};
      #pragma unroll
      for (int sub = 0; sub < 4; ++sub){
        int row = 16 * sub + r;
        u16x8 kf0 = *(const u16x8*)&kt[cur][row * 64 + ((g4       ^ (row & 7)) * 8)];
        u16x8 kf1 = *(const u16x8*)&kt[cur][row * 64 + (((4 + g4) ^ (row & 7)) * 8)];
        mfma16(p[sub], qf0, kf0);
        mfma16(p[sub], qf1, kf1);
      }
      asm volatile("s_nop 7\n\ts_nop 7"
                   : "+v"(p[0]), "+v"(p[1]), "+v"(p[2]), "+v"(p[3]));
      float arr[4];
      #pragma unroll
      for (int rr = 0; rr < 4; ++rr)
        arr[rr] = exp2f((float)(s0w + 4 * g4 + rr - tb) * l2g) * invn[rr];
      #pragma unroll
      for (int sub = 0; sub < 4; ++sub){
        int tt = tb + 16 * sub + r;
        #pragma unroll
        for (int rr = 0; rr < 4; ++rr){
          int srow = s0w + 4 * g4 + rr;
          float dec = (srow >= tt) ? arr[rr] * bsub[sub] : 0.0f;
          float val = p[sub][rr] * dec;
          rs[rr] += val;
          pb[w][(4 * g4 + rr) * 88 + 16 * sub + r] = f2bf(val);
        }
      }
      asm volatile("s_waitcnt lgkmcnt(0)" ::: "memory");
      __builtin_amdgcn_sched_barrier(0);
      u16x8 pf0 = *(const u16x8*)&pb[w][r * 88 + 8 * g4];
      u16x8 pf1 = *(const u16x8*)&pb[w][r * 88 + 32 + 8 * g4];
      #pragma unroll
      for (int cs = 0; cs < 8; ++cs){
        int row = 16 * cs + r;
        u16x8 vf0 = *(const u16x8*)&vt[cur][row * 64 + ((g4       ^ (row & 7)) * 8)];
        u16x8 vf1 = *(const u16x8*)&vt[cur][row * 64 + (((4 + g4) ^ (row & 7)) * 8)];
        mfma16(oacc[cs], pf0, vf0);
        mfma16(oacc[cs], pf1, vf1);
      }
    }
    asm volatile("s_waitcnt lgkmcnt(0)" ::: "memory");
    __builtin_amdgcn_s_barrier();
    cur ^= 1;
  }

  #pragma unroll
  for (int rr = 0; rr < 4; ++rr){
    float v = rs[rr];
    v += __shfl_xor(v, 1); v += __shfl_xor(v, 2);
    v += __shfl_xor(v, 4); v += __shfl_xor(v, 8);
    float den = fabsf(v); if (den < 1.0f) den = 1.0f;
    rs[rr] = 1.0f / den;
  }
  #pragma unroll
  for (int cs = 0; cs < 8; ++cs)
    #pragma unroll
    for (int rr = 0; rr < 4; ++rr){
      int s = s0w + 4 * g4 + rr;
      obuf[((size_t)h * S_LEN + s) * 128 + 16 * cs + r] = oacc[cs][rr] * rs[rr];
    }
}

// ---------------- groupnorm + silu gate ----------------
__global__ __launch_bounds__(256) void gn_gate_kernel(const float* __restrict__ obuf,
                                                      const u16* __restrict__ gb,
                                                      const float* __restrict__ gnw,
                                                      const float* __restrict__ gnb,
                                                      u16* __restrict__ gated){
  int s = blockIdx.x;
  int w = threadIdx.x >> 6, lane = threadIdx.x & 63;
  for (int h = w; h < 16; h += 4){
    const float* op = obuf + ((size_t)h * S_LEN + s) * 128 + lane * 2;
    float v0 = op[0], v1 = op[1];
    float sum = v0 + v1;
    #pragma unroll
    for (int m = 1; m < 64; m <<= 1) sum += __shfl_xor(sum, m);
    float mu = sum * (1.0f / 128.0f);
    float d0 = v0 - mu, d1 = v1 - mu;
    float sq = d0 * d0 + d1 * d1;
    #pragma unroll
    for (int m = 1; m < 64; m <<= 1) sq += __shfl_xor(sq, m);
    float rstd = rsqrtf(sq * (1.0f / 128.0f) + 1e-5f);
    int c = h * 128 + lane * 2;
    float n0 = d0 * rstd * gnw[c]     + gnb[c];
    float n1 = d1 * rstd * gnw[c + 1] + gnb[c + 1];
    u16x2 gv = *(const u16x2*)(gb + (size_t)s * 2048 + c);
    float g0 = bf2f(gv[0]), g1 = bf2f(gv[1]);
    float r0 = g0 / (1.0f + __expf(-g0)) * n0;   // g*sigmoid(g)*o
    float r1 = g1 / (1.0f + __expf(-g1)) * n1;
    u16x2 o2; o2[0] = f2bf(r0); o2[1] = f2bf(r1);
    *(u16x2*)(gated + (size_t)s * 2048 + c) = o2;
  }
}

// ---------------- launcher ----------------
extern "C" void kernel_launch(void* const* d_in, const int* in_sizes, int n_in,
                              void* d_out, int out_size, void* d_ws, size_t ws_size,
                              hipStream_t stream)
{
  (void)in_sizes; (void)n_in; (void)out_size; (void)ws_size;
  const float* x    = (const float*)d_in[0];
  const float* sinb = (const float*)d_in[1];
  const float* cosb = (const float*)d_in[2];
  // d_in[3] = mask : recomputed on the fly, never read (saves 268 MB)
  const float* Wq   = (const float*)d_in[4];
  const float* Wk   = (const float*)d_in[5];
  const float* Wv   = (const float*)d_in[6];
  const float* Wg   = (const float*)d_in[7];
  const float* Wo   = (const float*)d_in[8];
  const float* gnw  = (const float*)d_in[9];
  const float* gnb  = (const float*)d_in[10];
  float* out = (float*)d_out;

  // workspace layout (lifetime-overlapped, peak 44 MB)
  char* ws = (char*)d_ws;
  u16*   xb    = (u16*)  (ws + 0);                  // 4MB   (dead after proj)
  u16*   WT    = (u16*)  (ws + ((size_t)4  << 20)); // 12MB  q|k|v|g weights^T (dead after proj)
  float* obuf  = (float*)(ws + 0);                  // 16MB  (retention -> gn_gate)
  u16*   WoT   = (u16*)  (ws + ((size_t)16 << 20)); // 4MB
  u16*   qrb   = (u16*)  (ws + ((size_t)20 << 20)); // 4MB   (dead after retention)
  u16*   krb   = (u16*)  (ws + ((size_t)24 << 20)); // 4MB   (dead after retention)
  u16*   gated = (u16*)  (ws + ((size_t)20 << 20)); // 8MB   (gn_gate -> out-proj)
  u16*   vTb   = (u16*)  (ws + ((size_t)28 << 20)); // 8MB
  u16*   gbuf  = (u16*)  (ws + ((size_t)36 << 20)); // 8MB

  // L1: prep — convert x; fused transpose of all weights (k-scaling folded)
  cvt_x_kernel<<<dim3(2048), dim3(256), 0, stream>>>(x, xb);
  transpose_all<<<dim3(8192), dim3(256), 0, stream>>>(Wq, Wk, Wv, Wg, Wo, WT, WoT);

  // L2: merged q|k|v|g projection (N=6144), rope fused -> qrb,krb,vTb,gbuf
  gemm2<0, 128><<<dim3(48, 16), dim3(256), 0, stream>>>(xb, WT, 1024,
      nullptr, qrb, krb, vTb, gbuf, sinb, cosb);

  // L3: retention -> obuf [h][s][128] f32
  retention2<<<dim3(512), dim3(256), 0, stream>>>(qrb, krb, vTb, obuf);

  // L4: groupnorm + silu gate -> gated [s][2048] bf16
  gn_gate_kernel<<<dim3(2048), dim3(256), 0, stream>>>(obuf, gbuf, gnw, gnb, gated);

  // L5: final projection -> d_out f32 [2048][1024]  (BN=64 -> 256 blocks)
  gemm2<2, 64><<<dim3(16, 16), dim3(256), 0, stream>>>(gated, WoT, 2048,
      out, nullptr, nullptr, nullptr, nullptr, nullptr, nullptr);
}

// Round 6
// 136.619 us; speedup vs baseline: 2.1586x; 1.0689x over previous
//
#include <hip/hip_runtime.h>
#include <cstdint>
#include <cstddef>

// ---------------- types / helpers ----------------
typedef unsigned short u16;
typedef u16   u16x8 __attribute__((ext_vector_type(8)));
typedef u16   u16x4 __attribute__((ext_vector_type(4)));
typedef u16   u16x2 __attribute__((ext_vector_type(2)));
typedef float f32x4 __attribute__((ext_vector_type(4)));

#define S_LEN 2048

static __device__ __forceinline__ u16 f2bf(float f){
  union { float f; unsigned u; } v; v.f = f;
  unsigned r = (v.u + 0x7FFFu + ((v.u >> 16) & 1u)) >> 16;   // RNE
  return (u16)r;
}
static __device__ __forceinline__ float bf2f(u16 u){
  union { unsigned u; float f; } v; v.u = ((unsigned)u) << 16; return v.f;
}

// mfma_f32_16x16x32_bf16 via inline asm.
//   A: lane holds A[lane&15][8*(lane>>4)+j]
//   B: lane holds B[8*(lane>>4)+j][lane&15]
//   D: lane reg r holds D[4*(lane>>4)+r][lane&15]
static __device__ __forceinline__ void mfma16(f32x4& c, u16x8 a, u16x8 b){
  asm("s_nop 1\n\tv_mfma_f32_16x16x32_bf16 %0, %1, %2, %0"
      : "+v"(c) : "v"(a), "v"(b));
}

#if defined(__has_builtin)
#  if __has_builtin(__builtin_amdgcn_global_load_lds)
#    define USE_GLDS 1
#  endif
#endif

static __device__ __forceinline__ void stage16(const u16* g, u16* l){
#ifdef USE_GLDS
  __builtin_amdgcn_global_load_lds((const __attribute__((address_space(1))) void*)g,
                                   (__attribute__((address_space(3))) void*)l,
                                   16, 0, 0);
#else
  *(u16x8*)l = *(const u16x8*)g;   // reg-staged fallback
#endif
}

// ---------------- fused prep: x->bf16 + all 5 weight transposes ----------------
// bid segments: [0,1024) Wq | [1024,2048) Wk(x0.125) | [2048,4096) Wv
//               [4096,6144) Wg | [6144,8192) Wo | [8192,10240) cvt x
__global__ __launch_bounds__(256) void prep_all(
    const float* __restrict__ x, u16* __restrict__ xb,
    const float* __restrict__ Wq, const float* __restrict__ Wk,
    const float* __restrict__ Wv, const float* __restrict__ Wg,
    const float* __restrict__ Wo, u16* __restrict__ WT, u16* __restrict__ WoT){
  __shared__ float tile[32][33];
  int bid = blockIdx.x;
  if (bid >= 8192){                                   // x f32 -> bf16
    int i = ((bid - 8192) * 256 + threadIdx.x) * 4;
    float4 v = *(const float4*)(x + i);
    u16x4 o; o[0] = f2bf(v.x); o[1] = f2bf(v.y); o[2] = f2bf(v.z); o[3] = f2bf(v.w);
    *(u16x4*)(xb + i) = o;
    return;
  }
  const float* W; u16* dst; int K, N, lb, lgx; float scale = 1.0f;
  if (bid < 1024)      { W=Wq; dst=WT;                        K=1024; N=1024; lb=bid;        lgx=5; }
  else if (bid < 2048) { W=Wk; dst=WT + (size_t)1024 * 1024;  K=1024; N=1024; lb=bid - 1024; lgx=5; scale=0.125f; }
  else if (bid < 4096) { W=Wv; dst=WT + (size_t)2048 * 1024;  K=1024; N=2048; lb=bid - 2048; lgx=6; }
  else if (bid < 6144) { W=Wg; dst=WT + (size_t)4096 * 1024;  K=1024; N=2048; lb=bid - 4096; lgx=6; }
  else                 { W=Wo; dst=WoT;                       K=2048; N=1024; lb=bid - 6144; lgx=5; }
  int n0 = (lb & ((1 << lgx) - 1)) * 32;
  int k0 = (lb >> lgx) * 32;
  int tx = threadIdx.x & 31, ty = threadIdx.x >> 5;   // 32x8
  #pragma unroll
  for (int i = 0; i < 32; i += 8)
    tile[ty + i][tx] = W[(size_t)(k0 + ty + i) * N + n0 + tx];
  __syncthreads();
  #pragma unroll
  for (int i = 0; i < 32; i += 8)
    dst[(size_t)(n0 + ty + i) * K + k0 + tx] = f2bf(scale * tile[tx][ty + i]);
}

// ---------------- pipelined GEMM: C = A(bf16 MxK) @ BT(bf16 NxK)^T -------------
// BM=128, BK=64, 4 waves (2m x 2n). Double-buffered LDS, global_load_lds with
// XOR chunk swizzle (linear LDS dest, pre-swizzled global source), counted
// vmcnt so next-tile loads fly across the barrier, raw s_barrier.
// MODE 0: merged projection epilogue over n in [0,6144)
// MODE 2: f32 row-major out (N=1024)
template<int MODE, int BN>
__global__ __launch_bounds__(256) void gemm2(
    const u16* __restrict__ A, const u16* __restrict__ BT, int K,
    float* __restrict__ outF,
    u16* __restrict__ oq, u16* __restrict__ ok,
    u16* __restrict__ ovT, u16* __restrict__ og,
    const float* __restrict__ sinb, const float* __restrict__ cosb)
{
  constexpr int NI = BN / 32;              // n-fragments per wave
  constexpr int LB_LOADS = BN * 8 / 256;   // lB chunks per thread
  constexpr int TL = 4 + LB_LOADS;         // loads per thread per tile

  __shared__ u16 lA[2][128 * 64];
  __shared__ u16 lB[2][BN * 64];

  const int t = threadIdx.x;
  const int lane = t & 63, w = t >> 6;
  const int r = lane & 15, g4 = lane >> 4;
  const int bm = blockIdx.y * 128, bn = blockIdx.x * BN;
  const int wm = (w & 1) * 64, wn = (w >> 1) * (BN / 2);

  f32x4 acc[4][NI] = {};

  auto STAGE = [&](int buf, int kb){
    #pragma unroll
    for (int p = 0; p < 4; ++p){                       // lA: 1024 chunks
      int ci = p * 256 + t;
      int row = ci >> 3, ch = ci & 7;
      stage16(A + (size_t)(bm + row) * K + kb + ((ch ^ (row & 7)) * 8),
              &lA[buf][ci * 8]);
    }
    #pragma unroll
    for (int p = 0; p < LB_LOADS; ++p){                // lB: BN*8 chunks
      int ci = p * 256 + t;
      int row = ci >> 3, ch = ci & 7;
      stage16(BT + (size_t)(bn + row) * K + kb + ((ch ^ (row & 7)) * 8),
              &lB[buf][ci * 8]);
    }
  };

  STAGE(0, 0);
  int cur = 0;
  for (int kb = 0; kb < K; kb += 64){
    if (kb + 64 < K){
      STAGE(cur ^ 1, kb + 64);                         // prefetch next tile
      if constexpr (TL == 8) asm volatile("s_waitcnt vmcnt(8)" ::: "memory");
      else                   asm volatile("s_waitcnt vmcnt(6)" ::: "memory");
    } else {
      asm volatile("s_waitcnt vmcnt(0)" ::: "memory");
    }
    __builtin_amdgcn_s_barrier();                      // buf[cur] valid

    #pragma unroll
    for (int j = 0; j < 2; ++j){                       // two K=32 sub-steps
      u16x8 af[4], bfr[NI];
      #pragma unroll
      for (int i = 0; i < 4; ++i){
        int row = wm + 16 * i + r;
        af[i] = *(const u16x8*)&lA[cur][row * 64 + (((j * 4 + g4) ^ (row & 7)) * 8)];
      }
      #pragma unroll
      for (int i = 0; i < NI; ++i){
        int row = wn + 16 * i + r;
        bfr[i] = *(const u16x8*)&lB[cur][row * 64 + (((j * 4 + g4) ^ (row & 7)) * 8)];
      }
      #pragma unroll
      for (int mi = 0; mi < 4; ++mi)
        #pragma unroll
        for (int ni = 0; ni < NI; ++ni)
          mfma16(acc[mi][ni], af[mi], bfr[ni]);
    }
    asm volatile("s_waitcnt lgkmcnt(0)" ::: "memory"); // reads drained
    __builtin_amdgcn_s_barrier();                      // safe to overwrite buf[cur]
    cur ^= 1;
  }

  if constexpr (MODE == 2){
    #pragma unroll
    for (int mi = 0; mi < 4; ++mi)
      #pragma unroll
      for (int ni = 0; ni < NI; ++ni)
        #pragma unroll
        for (int rr = 0; rr < 4; ++rr){
          int row = bm + wm + 16 * mi + 4 * g4 + rr;
          int col = bn + wn + 16 * ni + r;
          outF[(size_t)row * 1024 + col] = acc[mi][ni][rr];
        }
  } else {
    if (bn < 2048){                                    // q | k with rope
      #pragma unroll
      for (int mi = 0; mi < 4; ++mi)
        #pragma unroll
        for (int ni = 0; ni < NI; ++ni){
          int n = bn + wn + 16 * ni + r;
          int kd = n & 63;
          #pragma unroll
          for (int rr = 0; rr < 4; ++rr){
            int srow = bm + wm + 16 * mi + 4 * g4 + rr;
            float v = acc[mi][ni][rr];
            float pv = __shfl_xor(v, 1);               // rope partner col (n^1)
            float cs = cosb[srow * 64 + kd];
            float sn = sinb[srow * 64 + kd];
            float o = v * cs + ((n & 1) ? pv : -pv) * sn;
            u16 ob = f2bf(o);
            if (n < 1024) oq[((size_t)(n >> 6)          * S_LEN + srow) * 64 + kd] = ob;
            else          ok[((size_t)((n - 1024) >> 6) * S_LEN + srow) * 64 + kd] = ob;
          }
        }
    } else if (bn < 4096){                             // vT[n][s]
      #pragma unroll
      for (int mi = 0; mi < 4; ++mi)
        #pragma unroll
        for (int ni = 0; ni < NI; ++ni){
          int n = (bn - 2048) + wn + 16 * ni + r;
          int srow0 = bm + wm + 16 * mi + 4 * g4;
          u16x4 pk;
          #pragma unroll
          for (int rr = 0; rr < 4; ++rr) pk[rr] = f2bf(acc[mi][ni][rr]);
          *(u16x4*)&ovT[(size_t)n * S_LEN + srow0] = pk;
        }
    } else {                                           // g[s][n]
      #pragma unroll
      for (int mi = 0; mi < 4; ++mi)
        #pragma unroll
        for (int ni = 0; ni < NI; ++ni){
          int n = (bn - 4096) + wn + 16 * ni + r;
          int srow0 = bm + wm + 16 * mi + 4 * g4;
          #pragma unroll
          for (int rr = 0; rr < 4; ++rr)
            og[(size_t)(srow0 + rr) * 2048 + n] = f2bf(acc[mi][ni][rr]);
        }
    }
  }
}

// ---------------- retention + fused groupnorm + silu gate ----------------
// Core loop identical to R4/R5-verified retention2. Epilogue now applies den,
// then groupnorm over the 128 channels the wave already holds (two-pass:
// shfl-reduce mean, then centered sumsq), then silu(g)*norm, writing gated
// bf16 directly (obuf + gn_gate kernel eliminated).
__global__ __launch_bounds__(256) void retention_gn(const u16* __restrict__ qrb,
                                                    const u16* __restrict__ krb,
                                                    const u16* __restrict__ vTb,
                                                    const u16* __restrict__ gbuf,
                                                    const float* __restrict__ gnw,
                                                    const float* __restrict__ gnb,
                                                    u16* __restrict__ gated){
  __shared__ u16 kt[2][64 * 64];    // [t-row 64][kd 64], chunk-swizzled
  __shared__ u16 vt[2][128 * 64];   // [c-row 128][t 64], chunk-swizzled
  __shared__ u16 pb[4][16 * 88];    // per-wave P transpose

  const int idx = blockIdx.x;
  const int h  = idx & 15;
  const int sb = (idx < 256) ? (31 - (idx >> 4)) : ((idx >> 4) - 16);
  const int s0 = sb * 64;
  const int t  = threadIdx.x;
  const int w  = t >> 6, lane = t & 63;
  const int r  = lane & 15, g4 = lane >> 4;
  const int s0w = s0 + 16 * w;

  const float om   = exp2f(-5.0f - (float)h);       // 1-gamma, exact
  const float lg   = logf(1.0f - om);
  const float l2g  = lg * 1.44269504088896f;        // negative
  const float dmax = 30.0f / (-l2g);

  int t0 = 0;
  {
    float tf = (float)(s0 - 63) - dmax;
    if (tf > 0.0f) t0 = ((int)tf) & ~63;
  }

  const u16* qrow = qrb + ((size_t)h * S_LEN + (s0w + r)) * 64 + 8 * g4;
  u16x8 qf0 = *(const u16x8*)(qrow);
  u16x8 qf1 = *(const u16x8*)(qrow + 32);

  float invn[4];
  #pragma unroll
  for (int rr = 0; rr < 4; ++rr){
    int s = s0w + 4 * g4 + rr;
    invn[rr] = rsqrtf(-expm1f((float)(s + 1) * lg) / om);
  }
  float bsub[4];
  {
    float e_r  = exp2f(-(float)r * l2g);
    float e16  = exp2f(-16.0f * l2g);
    bsub[0] = e_r; bsub[1] = bsub[0] * e16; bsub[2] = bsub[1] * e16; bsub[3] = bsub[2] * e16;
  }

  f32x4 oacc[8] = {};
  float rs[4] = {0.f, 0.f, 0.f, 0.f};

  auto STAGE = [&](int buf, int tb){
    #pragma unroll
    for (int p = 0; p < 2; ++p){                 // K: 512 chunks
      int ci = p * 256 + t;
      int row = ci >> 3, ch = ci & 7;
      const u16* src = krb + ((size_t)h * S_LEN + tb + row) * 64 + ((ch ^ (row & 7)) * 8);
      stage16(src, &kt[buf][ci * 8]);
    }
    #pragma unroll
    for (int p = 0; p < 4; ++p){                 // V: 1024 chunks
      int ci = p * 256 + t;
      int row = ci >> 3, ch = ci & 7;
      const u16* src = vTb + ((size_t)(h * 128 + row)) * S_LEN + tb + ((ch ^ (row & 7)) * 8);
      stage16(src, &vt[buf][ci * 8]);
    }
  };

  STAGE(0, t0);
  int cur = 0;
  for (int tb = t0; tb <= s0; tb += 64){
    const bool last = (tb + 64 > s0);
    if (!last){
      STAGE(cur ^ 1, tb + 64);
      asm volatile("s_waitcnt vmcnt(6)" ::: "memory");
    } else {
      asm volatile("s_waitcnt vmcnt(0)" ::: "memory");
    }
    __builtin_amdgcn_s_barrier();

    if (tb <= s0w + 15 && (float)(s0w - tb - 63) <= dmax){
      f32x4 p[4] = {};
      #pragma unroll
      for (int sub = 0; sub < 4; ++sub){
        int row = 16 * sub + r;
        u16x8 kf0 = *(const u16x8*)&kt[cur][row * 64 + ((g4       ^ (row & 7)) * 8)];
        u16x8 kf1 = *(const u16x8*)&kt[cur][row * 64 + (((4 + g4) ^ (row & 7)) * 8)];
        mfma16(p[sub], qf0, kf0);
        mfma16(p[sub], qf1, kf1);
      }
      asm volatile("s_nop 7\n\ts_nop 7"
                   : "+v"(p[0]), "+v"(p[1]), "+v"(p[2]), "+v"(p[3]));
      float arr[4];
      #pragma unroll
      for (int rr = 0; rr < 4; ++rr)
        arr[rr] = exp2f((float)(s0w + 4 * g4 + rr - tb) * l2g) * invn[rr];
      #pragma unroll
      for (int sub = 0; sub < 4; ++sub){
        int tt = tb + 16 * sub + r;
        #pragma unroll
        for (int rr = 0; rr < 4; ++rr){
          int srow = s0w + 4 * g4 + rr;
          float dec = (srow >= tt) ? arr[rr] * bsub[sub] : 0.0f;
          float val = p[sub][rr] * dec;
          rs[rr] += val;
          pb[w][(4 * g4 + rr) * 88 + 16 * sub + r] = f2bf(val);
        }
      }
      asm volatile("s_waitcnt lgkmcnt(0)" ::: "memory");
      __builtin_amdgcn_sched_barrier(0);
      u16x8 pf0 = *(const u16x8*)&pb[w][r * 88 + 8 * g4];
      u16x8 pf1 = *(const u16x8*)&pb[w][r * 88 + 32 + 8 * g4];
      #pragma unroll
      for (int cs = 0; cs < 8; ++cs){
        int row = 16 * cs + r;
        u16x8 vf0 = *(const u16x8*)&vt[cur][row * 64 + ((g4       ^ (row & 7)) * 8)];
        u16x8 vf1 = *(const u16x8*)&vt[cur][row * 64 + (((4 + g4) ^ (row & 7)) * 8)];
        mfma16(oacc[cs], pf0, vf0);
        mfma16(oacc[cs], pf1, vf1);
      }
    }
    asm volatile("s_waitcnt lgkmcnt(0)" ::: "memory");
    __builtin_amdgcn_s_barrier();
    cur ^= 1;
  }

  // ---- den ----
  #pragma unroll
  for (int rr = 0; rr < 4; ++rr){
    float v = rs[rr];
    v += __shfl_xor(v, 1); v += __shfl_xor(v, 2);
    v += __shfl_xor(v, 4); v += __shfl_xor(v, 8);
    float den = fabsf(v); if (den < 1.0f) den = 1.0f;
    rs[rr] = 1.0f / den;
  }

  // ---- fused groupnorm + silu gate ----
  // Row s = s0w + 4*g4 + rr spans 16 lanes (r) x 8 regs (cs); col = 16*cs + r.
  float gw[8], gbv[8];
  #pragma unroll
  for (int cs = 0; cs < 8; ++cs){
    int gc = h * 128 + 16 * cs + r;
    gw[cs]  = gnw[gc];
    gbv[cs] = gnb[gc];
  }
  #pragma unroll
  for (int rr = 0; rr < 4; ++rr){
    int s = s0w + 4 * g4 + rr;
    float vv[8], m = 0.0f;
    #pragma unroll
    for (int cs = 0; cs < 8; ++cs){ vv[cs] = oacc[cs][rr] * rs[rr]; m += vv[cs]; }
    m += __shfl_xor(m, 1); m += __shfl_xor(m, 2);
    m += __shfl_xor(m, 4); m += __shfl_xor(m, 8);
    float mu = m * (1.0f / 128.0f);
    float sq = 0.0f;
    #pragma unroll
    for (int cs = 0; cs < 8; ++cs){ float d = vv[cs] - mu; sq += d * d; }
    sq += __shfl_xor(sq, 1); sq += __shfl_xor(sq, 2);
    sq += __shfl_xor(sq, 4); sq += __shfl_xor(sq, 8);
    float rstd = rsqrtf(sq * (1.0f / 128.0f) + 1e-5f);
    #pragma unroll
    for (int cs = 0; cs < 8; ++cs){
      int gc = h * 128 + 16 * cs + r;
      float nv = (vv[cs] - mu) * rstd * gw[cs] + gbv[cs];
      float gv = bf2f(gbuf[(size_t)s * 2048 + gc]);
      float res = gv / (1.0f + __expf(-gv)) * nv;    // g*sigmoid(g)*norm
      gated[(size_t)s * 2048 + gc] = f2bf(res);
    }
  }
}

// ---------------- launcher ----------------
extern "C" void kernel_launch(void* const* d_in, const int* in_sizes, int n_in,
                              void* d_out, int out_size, void* d_ws, size_t ws_size,
                              hipStream_t stream)
{
  (void)in_sizes; (void)n_in; (void)out_size; (void)ws_size;
  const float* x    = (const float*)d_in[0];
  const float* sinb = (const float*)d_in[1];
  const float* cosb = (const float*)d_in[2];
  // d_in[3] = mask : recomputed on the fly, never read (saves 268 MB)
  const float* Wq   = (const float*)d_in[4];
  const float* Wk   = (const float*)d_in[5];
  const float* Wv   = (const float*)d_in[6];
  const float* Wg   = (const float*)d_in[7];
  const float* Wo   = (const float*)d_in[8];
  const float* gnw  = (const float*)d_in[9];
  const float* gnb  = (const float*)d_in[10];
  float* out = (float*)d_out;

  // workspace layout (lifetime-overlapped)
  char* ws = (char*)d_ws;
  u16*   xb    = (u16*)  (ws + 0);                  // 4MB  (dead after proj)
  u16*   WT    = (u16*)  (ws + ((size_t)4  << 20)); // 12MB (dead after proj)
  u16*   gated = (u16*)  (ws + 0);                  // 8MB  (retention -> out-proj; reuses xb/WT)
  u16*   WoT   = (u16*)  (ws + ((size_t)16 << 20)); // 4MB
  u16*   qrb   = (u16*)  (ws + ((size_t)20 << 20)); // 4MB  (dead after retention)
  u16*   krb   = (u16*)  (ws + ((size_t)24 << 20)); // 4MB  (dead after retention)
  u16*   vTb   = (u16*)  (ws + ((size_t)28 << 20)); // 8MB
  u16*   gbuf  = (u16*)  (ws + ((size_t)36 << 20)); // 8MB

  // L1: fused prep — weight transposes (k-scaling folded) + x conversion
  prep_all<<<dim3(10240), dim3(256), 0, stream>>>(x, xb, Wq, Wk, Wv, Wg, Wo, WT, WoT);

  // L2: merged q|k|v|g projection (N=6144), rope fused -> qrb,krb,vTb,gbuf
  gemm2<0, 128><<<dim3(48, 16), dim3(256), 0, stream>>>(xb, WT, 1024,
      nullptr, qrb, krb, vTb, gbuf, sinb, cosb);

  // L3: retention + groupnorm + silu gate -> gated [s][2048] bf16
  retention_gn<<<dim3(512), dim3(256), 0, stream>>>(qrb, krb, vTb, gbuf, gnw, gnb, gated);

  // L4: final projection -> d_out f32 [2048][1024]  (BN=64 -> 256 blocks)
  gemm2<2, 64><<<dim3(16, 16), dim3(256), 0, stream>>>(gated, WoT, 2048,
      out, nullptr, nullptr, nullptr, nullptr, nullptr, nullptr);
}

// Round 7
// 121.216 us; speedup vs baseline: 2.4329x; 1.1271x over previous
//
#include <hip/hip_runtime.h>
#include <cstdint>
#include <cstddef>

// ---------------- types / helpers ----------------
typedef unsigned short u16;
typedef u16   u16x8 __attribute__((ext_vector_type(8)));
typedef u16   u16x4 __attribute__((ext_vector_type(4)));
typedef u16   u16x2 __attribute__((ext_vector_type(2)));
typedef float f32x4 __attribute__((ext_vector_type(4)));

#define S_LEN 2048

static __device__ __forceinline__ u16 f2bf(float f){
  union { float f; unsigned u; } v; v.f = f;
  unsigned r = (v.u + 0x7FFFu + ((v.u >> 16) & 1u)) >> 16;   // RNE
  return (u16)r;
}
static __device__ __forceinline__ float bf2f(u16 u){
  union { unsigned u; float f; } v; v.u = ((unsigned)u) << 16; return v.f;
}

// mfma_f32_16x16x32_bf16 via inline asm.
//   A: lane holds A[lane&15][8*(lane>>4)+j]
//   B: lane holds B[8*(lane>>4)+j][lane&15]
//   D: lane reg r holds D[4*(lane>>4)+r][lane&15]
static __device__ __forceinline__ void mfma16(f32x4& c, u16x8 a, u16x8 b){
  asm("s_nop 1\n\tv_mfma_f32_16x16x32_bf16 %0, %1, %2, %0"
      : "+v"(c) : "v"(a), "v"(b));
}

#if defined(__has_builtin)
#  if __has_builtin(__builtin_amdgcn_global_load_lds)
#    define USE_GLDS 1
#  endif
#endif

static __device__ __forceinline__ void stage16(const u16* g, u16* l){
#ifdef USE_GLDS
  __builtin_amdgcn_global_load_lds((const __attribute__((address_space(1))) void*)g,
                                   (__attribute__((address_space(3))) void*)l,
                                   16, 0, 0);
#else
  *(u16x8*)l = *(const u16x8*)g;   // reg-staged fallback
#endif
}

// ---------------- fused prep: x->bf16 + all 5 weight transposes ----------------
// bid segments: [0,1024) Wq | [1024,2048) Wk(x0.125) | [2048,4096) Wv
//               [4096,6144) Wg | [6144,8192) Wo | [8192,10240) cvt x
__global__ __launch_bounds__(256) void prep_all(
    const float* __restrict__ x, u16* __restrict__ xb,
    const float* __restrict__ Wq, const float* __restrict__ Wk,
    const float* __restrict__ Wv, const float* __restrict__ Wg,
    const float* __restrict__ Wo, u16* __restrict__ WT, u16* __restrict__ WoT){
  __shared__ float tile[32][33];
  int bid = blockIdx.x;
  if (bid >= 8192){                                   // x f32 -> bf16
    int i = ((bid - 8192) * 256 + threadIdx.x) * 4;
    float4 v = *(const float4*)(x + i);
    u16x4 o; o[0] = f2bf(v.x); o[1] = f2bf(v.y); o[2] = f2bf(v.z); o[3] = f2bf(v.w);
    *(u16x4*)(xb + i) = o;
    return;
  }
  const float* W; u16* dst; int K, N, lb, lgx; float scale = 1.0f;
  if (bid < 1024)      { W=Wq; dst=WT;                        K=1024; N=1024; lb=bid;        lgx=5; }
  else if (bid < 2048) { W=Wk; dst=WT + (size_t)1024 * 1024;  K=1024; N=1024; lb=bid - 1024; lgx=5; scale=0.125f; }
  else if (bid < 4096) { W=Wv; dst=WT + (size_t)2048 * 1024;  K=1024; N=2048; lb=bid - 2048; lgx=6; }
  else if (bid < 6144) { W=Wg; dst=WT + (size_t)4096 * 1024;  K=1024; N=2048; lb=bid - 4096; lgx=6; }
  else                 { W=Wo; dst=WoT;                       K=2048; N=1024; lb=bid - 6144; lgx=5; }
  int n0 = (lb & ((1 << lgx) - 1)) * 32;
  int k0 = (lb >> lgx) * 32;
  int tx = threadIdx.x & 31, ty = threadIdx.x >> 5;   // 32x8
  #pragma unroll
  for (int i = 0; i < 32; i += 8)
    tile[ty + i][tx] = W[(size_t)(k0 + ty + i) * N + n0 + tx];
  __syncthreads();
  #pragma unroll
  for (int i = 0; i < 32; i += 8)
    dst[(size_t)(n0 + ty + i) * K + k0 + tx] = f2bf(scale * tile[tx][ty + i]);
}

// ---------------- pipelined GEMM: C = A(bf16 MxK) @ BT(bf16 NxK)^T -------------
// BM=128, BK=64, 4 waves (2m x 2n). Double-buffered LDS, global_load_lds with
// XOR chunk swizzle (linear LDS dest, pre-swizzled global source), counted
// vmcnt so next-tile loads fly across the barrier, raw s_barrier.
// MODE 0: merged projection epilogue over n in [0,6144); outputs are routed
//         through an LDS bounce tile (reusing the dead double-buffer) so all
//         global stores are coalesced 16B chunks.
// MODE 2: f32 row-major out (N=1024)
template<int MODE, int BN>
__global__ __launch_bounds__(256) void gemm2(
    const u16* __restrict__ A, const u16* __restrict__ BT, int K,
    float* __restrict__ outF,
    u16* __restrict__ oq, u16* __restrict__ ok,
    u16* __restrict__ ovT, u16* __restrict__ og,
    const float* __restrict__ sinb, const float* __restrict__ cosb)
{
  constexpr int NI = BN / 32;              // n-fragments per wave
  constexpr int LB_LOADS = BN * 8 / 256;   // lB chunks per thread
  constexpr int TL = 4 + LB_LOADS;         // loads per thread per tile
  constexpr int LBOFF = 128 * 64;          // lB offset inside sh[buf]

  __shared__ u16 sh[2][128 * 64 + BN * 64];

  const int t = threadIdx.x;
  const int lane = t & 63, w = t >> 6;
  const int r = lane & 15, g4 = lane >> 4;
  const int bm = blockIdx.y * 128, bn = blockIdx.x * BN;
  const int wm = (w & 1) * 64, wn = (w >> 1) * (BN / 2);

  f32x4 acc[4][NI] = {};

  auto STAGE = [&](int buf, int kb){
    #pragma unroll
    for (int p = 0; p < 4; ++p){                       // lA: 1024 chunks
      int ci = p * 256 + t;
      int row = ci >> 3, ch = ci & 7;
      stage16(A + (size_t)(bm + row) * K + kb + ((ch ^ (row & 7)) * 8),
              &sh[buf][ci * 8]);
    }
    #pragma unroll
    for (int p = 0; p < LB_LOADS; ++p){                // lB: BN*8 chunks
      int ci = p * 256 + t;
      int row = ci >> 3, ch = ci & 7;
      stage16(BT + (size_t)(bn + row) * K + kb + ((ch ^ (row & 7)) * 8),
              &sh[buf][LBOFF + ci * 8]);
    }
  };

  STAGE(0, 0);
  int cur = 0;
  for (int kb = 0; kb < K; kb += 64){
    if (kb + 64 < K){
      STAGE(cur ^ 1, kb + 64);                         // prefetch next tile
      if constexpr (TL == 8) asm volatile("s_waitcnt vmcnt(8)" ::: "memory");
      else                   asm volatile("s_waitcnt vmcnt(6)" ::: "memory");
    } else {
      asm volatile("s_waitcnt vmcnt(0)" ::: "memory");
    }
    __builtin_amdgcn_s_barrier();                      // buf[cur] valid

    #pragma unroll
    for (int j = 0; j < 2; ++j){                       // two K=32 sub-steps
      u16x8 af[4], bfr[NI];
      #pragma unroll
      for (int i = 0; i < 4; ++i){
        int row = wm + 16 * i + r;
        af[i] = *(const u16x8*)&sh[cur][row * 64 + (((j * 4 + g4) ^ (row & 7)) * 8)];
      }
      #pragma unroll
      for (int i = 0; i < NI; ++i){
        int row = wn + 16 * i + r;
        bfr[i] = *(const u16x8*)&sh[cur][LBOFF + row * 64 + (((j * 4 + g4) ^ (row & 7)) * 8)];
      }
      #pragma unroll
      for (int mi = 0; mi < 4; ++mi)
        #pragma unroll
        for (int ni = 0; ni < NI; ++ni)
          mfma16(acc[mi][ni], af[mi], bfr[ni]);
    }
    asm volatile("s_waitcnt lgkmcnt(0)" ::: "memory"); // reads drained
    __builtin_amdgcn_s_barrier();                      // safe to overwrite buf[cur]
    cur ^= 1;
  }

  if constexpr (MODE == 2){
    #pragma unroll
    for (int mi = 0; mi < 4; ++mi)
      #pragma unroll
      for (int ni = 0; ni < NI; ++ni)
        #pragma unroll
        for (int rr = 0; rr < 4; ++rr){
          int row = bm + wm + 16 * mi + 4 * g4 + rr;
          int col = bn + wn + 16 * ni + r;
          outF[(size_t)row * 1024 + col] = acc[mi][ni][rr];
        }
  } else {
    // ---- LDS-bounce epilogue: reuse sh (dead after K-loop) as a 128x128
    // bf16 staging tile so all global stores are coalesced 16B chunks.
    u16* L = &sh[0][0];
    if (bn < 2048){                                    // q | k with rope
      constexpr int STR = 136;                         // row stride (16B-aligned)
      #pragma unroll
      for (int mi = 0; mi < 4; ++mi)
        #pragma unroll
        for (int ni = 0; ni < NI; ++ni){
          int nl = wn + 16 * ni + r;
          int n  = bn + nl;
          int kd = n & 63;
          #pragma unroll
          for (int rr = 0; rr < 4; ++rr){
            int sl = wm + 16 * mi + 4 * g4 + rr;
            int srow = bm + sl;
            float v = acc[mi][ni][rr];
            float pv = __shfl_xor(v, 1);               // rope partner col (n^1)
            float cs = cosb[srow * 64 + kd];
            float sn = sinb[srow * 64 + kd];
            float o = v * cs + ((n & 1) ? pv : -pv) * sn;
            L[sl * STR + nl] = f2bf(o);
          }
        }
      asm volatile("s_waitcnt lgkmcnt(0)" ::: "memory");
      __builtin_amdgcn_s_barrier();
      #pragma unroll
      for (int it = 0; it < 8; ++it){
        int id = it * 256 + t;
        int sl = id >> 4, c = id & 15, hb = c >> 3, kc = c & 7;
        u16x8 val = *(const u16x8*)&L[sl * STR + hb * 64 + kc * 8];
        int n0 = bn + hb * 64;                         // head col base
        u16* dst = (n0 < 1024)
          ? (oq + ((size_t)(n0 >> 6)          * S_LEN + bm + sl) * 64 + kc * 8)
          : (ok + ((size_t)((n0 - 1024) >> 6) * S_LEN + bm + sl) * 64 + kc * 8);
        *(u16x8*)dst = val;
      }
    } else if (bn < 4096){                             // vT[n][s]
      constexpr int STR = 137;                         // odd stride: spreads banks
      #pragma unroll
      for (int mi = 0; mi < 4; ++mi)
        #pragma unroll
        for (int ni = 0; ni < NI; ++ni){
          int nl = wn + 16 * ni + r;
          #pragma unroll
          for (int rr = 0; rr < 4; ++rr){
            int sl = wm + 16 * mi + 4 * g4 + rr;
            L[sl * STR + nl] = f2bf(acc[mi][ni][rr]);
          }
        }
      asm volatile("s_waitcnt lgkmcnt(0)" ::: "memory");
      __builtin_amdgcn_s_barrier();
      #pragma unroll
      for (int it = 0; it < 8; ++it){
        int id = it * 256 + t;
        int nl = id >> 4, sc = id & 15;
        u16x8 pk;
        #pragma unroll
        for (int j = 0; j < 8; ++j)
          pk[j] = L[(sc * 8 + j) * STR + nl];          // transposed gather (LDS)
        *(u16x8*)&ovT[(size_t)(bn - 2048 + nl) * S_LEN + bm + sc * 8] = pk;
      }
    } else {                                           // g[s][n]
      constexpr int STR = 136;
      #pragma unroll
      for (int mi = 0; mi < 4; ++mi)
        #pragma unroll
        for (int ni = 0; ni < NI; ++ni){
          int nl = wn + 16 * ni + r;
          #pragma unroll
          for (int rr = 0; rr < 4; ++rr){
            int sl = wm + 16 * mi + 4 * g4 + rr;
            L[sl * STR + nl] = f2bf(acc[mi][ni][rr]);
          }
        }
      asm volatile("s_waitcnt lgkmcnt(0)" ::: "memory");
      __builtin_amdgcn_s_barrier();
      #pragma unroll
      for (int it = 0; it < 8; ++it){
        int id = it * 256 + t;
        int sl = id >> 4, c = id & 15;
        u16x8 val = *(const u16x8*)&L[sl * STR + c * 8];
        *(u16x8*)&og[(size_t)(bm + sl) * 2048 + (bn - 4096) + c * 8] = val;
      }
    }
  }
}

// ---------------- retention + fused groupnorm + silu gate ----------------
// Core loop identical to R4/R5-verified retention2. Epilogue applies den,
// then groupnorm over the 128 channels the wave already holds, then
// silu(g)*norm, writing gated bf16 directly.
__global__ __launch_bounds__(256) void retention_gn(const u16* __restrict__ qrb,
                                                    const u16* __restrict__ krb,
                                                    const u16* __restrict__ vTb,
                                                    const u16* __restrict__ gbuf,
                                                    const float* __restrict__ gnw,
                                                    const float* __restrict__ gnb,
                                                    u16* __restrict__ gated){
  __shared__ u16 kt[2][64 * 64];    // [t-row 64][kd 64], chunk-swizzled
  __shared__ u16 vt[2][128 * 64];   // [c-row 128][t 64], chunk-swizzled
  __shared__ u16 pb[4][16 * 88];    // per-wave P transpose

  const int idx = blockIdx.x;
  const int h  = idx & 15;
  const int sb = (idx < 256) ? (31 - (idx >> 4)) : ((idx >> 4) - 16);
  const int s0 = sb * 64;
  const int t  = threadIdx.x;
  const int w  = t >> 6, lane = t & 63;
  const int r  = lane & 15, g4 = lane >> 4;
  const int s0w = s0 + 16 * w;

  const float om   = exp2f(-5.0f - (float)h);       // 1-gamma, exact
  const float lg   = logf(1.0f - om);
  const float l2g  = lg * 1.44269504088896f;        // negative
  const float dmax = 30.0f / (-l2g);

  int t0 = 0;
  {
    float tf = (float)(s0 - 63) - dmax;
    if (tf > 0.0f) t0 = ((int)tf) & ~63;
  }

  const u16* qrow = qrb + ((size_t)h * S_LEN + (s0w + r)) * 64 + 8 * g4;
  u16x8 qf0 = *(const u16x8*)(qrow);
  u16x8 qf1 = *(const u16x8*)(qrow + 32);

  float invn[4];
  #pragma unroll
  for (int rr = 0; rr < 4; ++rr){
    int s = s0w + 4 * g4 + rr;
    invn[rr] = rsqrtf(-expm1f((float)(s + 1) * lg) / om);
  }
  float bsub[4];
  {
    float e_r  = exp2f(-(float)r * l2g);
    float e16  = exp2f(-16.0f * l2g);
    bsub[0] = e_r; bsub[1] = bsub[0] * e16; bsub[2] = bsub[1] * e16; bsub[3] = bsub[2] * e16;
  }

  f32x4 oacc[8] = {};
  float rs[4] = {0.f, 0.f, 0.f, 0.f};

  auto STAGE = [&](int buf, int tb){
    #pragma unroll
    for (int p = 0; p < 2; ++p){                 // K: 512 chunks
      int ci = p * 256 + t;
      int row = ci >> 3, ch = ci & 7;
      const u16* src = krb + ((size_t)h * S_LEN + tb + row) * 64 + ((ch ^ (row & 7)) * 8);
      stage16(src, &kt[buf][ci * 8]);
    }
    #pragma unroll
    for (int p = 0; p < 4; ++p){                 // V: 1024 chunks
      int ci = p * 256 + t;
      int row = ci >> 3, ch = ci & 7;
      const u16* src = vTb + ((size_t)(h * 128 + row)) * S_LEN + tb + ((ch ^ (row & 7)) * 8);
      stage16(src, &vt[buf][ci * 8]);
    }
  };

  STAGE(0, t0);
  int cur = 0;
  for (int tb = t0; tb <= s0; tb += 64){
    const bool last = (tb + 64 > s0);
    if (!last){
      STAGE(cur ^ 1, tb + 64);
      asm volatile("s_waitcnt vmcnt(6)" ::: "memory");
    } else {
      asm volatile("s_waitcnt vmcnt(0)" ::: "memory");
    }
    __builtin_amdgcn_s_barrier();

    if (tb <= s0w + 15 && (float)(s0w - tb - 63) <= dmax){
      f32x4 p[4] = {};
      #pragma unroll
      for (int sub = 0; sub < 4; ++sub){
        int row = 16 * sub + r;
        u16x8 kf0 = *(const u16x8*)&kt[cur][row * 64 + ((g4       ^ (row & 7)) * 8)];
        u16x8 kf1 = *(const u16x8*)&kt[cur][row * 64 + (((4 + g4) ^ (row & 7)) * 8)];
        mfma16(p[sub], qf0, kf0);
        mfma16(p[sub], qf1, kf1);
      }
      asm volatile("s_nop 7\n\ts_nop 7"
                   : "+v"(p[0]), "+v"(p[1]), "+v"(p[2]), "+v"(p[3]));
      float arr[4];
      #pragma unroll
      for (int rr = 0; rr < 4; ++rr)
        arr[rr] = exp2f((float)(s0w + 4 * g4 + rr - tb) * l2g) * invn[rr];
      #pragma unroll
      for (int sub = 0; sub < 4; ++sub){
        int tt = tb + 16 * sub + r;
        #pragma unroll
        for (int rr = 0; rr < 4; ++rr){
          int srow = s0w + 4 * g4 + rr;
          float dec = (srow >= tt) ? arr[rr] * bsub[sub] : 0.0f;
          float val = p[sub][rr] * dec;
          rs[rr] += val;
          pb[w][(4 * g4 + rr) * 88 + 16 * sub + r] = f2bf(val);
        }
      }
      asm volatile("s_waitcnt lgkmcnt(0)" ::: "memory");
      __builtin_amdgcn_sched_barrier(0);
      u16x8 pf0 = *(const u16x8*)&pb[w][r * 88 + 8 * g4];
      u16x8 pf1 = *(const u16x8*)&pb[w][r * 88 + 32 + 8 * g4];
      #pragma unroll
      for (int cs = 0; cs < 8; ++cs){
        int row = 16 * cs + r;
        u16x8 vf0 = *(const u16x8*)&vt[cur][row * 64 + ((g4       ^ (row & 7)) * 8)];
        u16x8 vf1 = *(const u16x8*)&vt[cur][row * 64 + (((4 + g4) ^ (row & 7)) * 8)];
        mfma16(oacc[cs], pf0, vf0);
        mfma16(oacc[cs], pf1, vf1);
      }
    }
    asm volatile("s_waitcnt lgkmcnt(0)" ::: "memory");
    __builtin_amdgcn_s_barrier();
    cur ^= 1;
  }

  // ---- den ----
  #pragma unroll
  for (int rr = 0; rr < 4; ++rr){
    float v = rs[rr];
    v += __shfl_xor(v, 1); v += __shfl_xor(v, 2);
    v += __shfl_xor(v, 4); v += __shfl_xor(v, 8);
    float den = fabsf(v); if (den < 1.0f) den = 1.0f;
    rs[rr] = 1.0f / den;
  }

  // ---- fused groupnorm + silu gate ----
  float gw[8], gbv[8];
  #pragma unroll
  for (int cs = 0; cs < 8; ++cs){
    int gc = h * 128 + 16 * cs + r;
    gw[cs]  = gnw[gc];
    gbv[cs] = gnb[gc];
  }
  #pragma unroll
  for (int rr = 0; rr < 4; ++rr){
    int s = s0w + 4 * g4 + rr;
    float vv[8], m = 0.0f;
    #pragma unroll
    for (int cs = 0; cs < 8; ++cs){ vv[cs] = oacc[cs][rr] * rs[rr]; m += vv[cs]; }
    m += __shfl_xor(m, 1); m += __shfl_xor(m, 2);
    m += __shfl_xor(m, 4); m += __shfl_xor(m, 8);
    float mu = m * (1.0f / 128.0f);
    float sq = 0.0f;
    #pragma unroll
    for (int cs = 0; cs < 8; ++cs){ float d = vv[cs] - mu; sq += d * d; }
    sq += __shfl_xor(sq, 1); sq += __shfl_xor(sq, 2);
    sq += __shfl_xor(sq, 4); sq += __shfl_xor(sq, 8);
    float rstd = rsqrtf(sq * (1.0f / 128.0f) + 1e-5f);
    #pragma unroll
    for (int cs = 0; cs < 8; ++cs){
      int gc = h * 128 + 16 * cs + r;
      float nv = (vv[cs] - mu) * rstd * gw[cs] + gbv[cs];
      float gv = bf2f(gbuf[(size_t)s * 2048 + gc]);
      float res = gv / (1.0f + __expf(-gv)) * nv;    // g*sigmoid(g)*norm
      gated[(size_t)s * 2048 + gc] = f2bf(res);
    }
  }
}

// ---------------- launcher ----------------
extern "C" void kernel_launch(void* const* d_in, const int* in_sizes, int n_in,
                              void* d_out, int out_size, void* d_ws, size_t ws_size,
                              hipStream_t stream)
{
  (void)in_sizes; (void)n_in; (void)out_size; (void)ws_size;
  const float* x    = (const float*)d_in[0];
  const float* sinb = (const float*)d_in[1];
  const float* cosb = (const float*)d_in[2];
  // d_in[3] = mask : recomputed on the fly, never read (saves 268 MB)
  const float* Wq   = (const float*)d_in[4];
  const float* Wk   = (const float*)d_in[5];
  const float* Wv   = (const float*)d_in[6];
  const float* Wg   = (const float*)d_in[7];
  const float* Wo   = (const float*)d_in[8];
  const float* gnw  = (const float*)d_in[9];
  const float* gnb  = (const float*)d_in[10];
  float* out = (float*)d_out;

  // workspace layout (lifetime-overlapped)
  char* ws = (char*)d_ws;
  u16*   xb    = (u16*)  (ws + 0);                  // 4MB  (dead after proj)
  u16*   WT    = (u16*)  (ws + ((size_t)4  << 20)); // 12MB (dead after proj)
  u16*   gated = (u16*)  (ws + 0);                  // 8MB  (retention -> out-proj; reuses xb/WT)
  u16*   WoT   = (u16*)  (ws + ((size_t)16 << 20)); // 4MB
  u16*   qrb   = (u16*)  (ws + ((size_t)20 << 20)); // 4MB  (dead after retention)
  u16*   krb   = (u16*)  (ws + ((size_t)24 << 20)); // 4MB  (dead after retention)
  u16*   vTb   = (u16*)  (ws + ((size_t)28 << 20)); // 8MB
  u16*   gbuf  = (u16*)  (ws + ((size_t)36 << 20)); // 8MB

  // L1: fused prep — weight transposes (k-scaling folded) + x conversion
  prep_all<<<dim3(10240), dim3(256), 0, stream>>>(x, xb, Wq, Wk, Wv, Wg, Wo, WT, WoT);

  // L2: merged q|k|v|g projection (N=6144), rope fused -> qrb,krb,vTb,gbuf
  gemm2<0, 128><<<dim3(48, 16), dim3(256), 0, stream>>>(xb, WT, 1024,
      nullptr, qrb, krb, vTb, gbuf, sinb, cosb);

  // L3: retention + groupnorm + silu gate -> gated [s][2048] bf16
  retention_gn<<<dim3(512), dim3(256), 0, stream>>>(qrb, krb, vTb, gbuf, gnw, gnb, gated);

  // L4: final projection -> d_out f32 [2048][1024]  (BN=64 -> 256 blocks)
  gemm2<2, 64><<<dim3(16, 16), dim3(256), 0, stream>>>(gated, WoT, 2048,
      out, nullptr, nullptr, nullptr, nullptr, nullptr, nullptr);
}